// Round 4
// baseline (712.706 us; speedup 1.0000x reference)
//
#include <hip/hip_runtime.h>

// QuantAttnBlock on gfx950, round 4: attention path rewritten.
// Softmax shift via Cauchy-Schwarz bound M = sc*|q|max*|k|max (exact on the
// quantized ints, cancels exactly in softmax) -> no max pass, no branchy
// online update. m-split grid (64 nt x 8 mchunk x 4 b = 2048 blocks) for full
// occupancy. i8 MFMA everywhere on the integer matmuls.

#define Bb 4
#define Cc 256
#define Nn 4096
#define NGRP 32
#define LOG2E 1.4426950408889634f

typedef unsigned short u16;
typedef unsigned int   u32;
typedef unsigned char  u8;
typedef __attribute__((ext_vector_type(8))) short bf16x8;
typedef __attribute__((ext_vector_type(4))) float f32x4;
typedef __attribute__((ext_vector_type(4))) int   i32x4;

#define MFMA16(a,b,c)    __builtin_amdgcn_mfma_f32_16x16x32_bf16((a),(b),(c),0,0,0)
#define MFMA_I8(a,b,c)   __builtin_amdgcn_mfma_i32_16x16x64_i8((a),(b),(c),0,0,0)

static __device__ __forceinline__ u16 f2bf(float x){
  u32 u = __float_as_uint(x);
  u += 0x7fffu + ((u >> 16) & 1u);
  return (u16)(u >> 16);
}
static __device__ __forceinline__ float bf2f(u16 h){ return __uint_as_float(((u32)h) << 16); }

union U64c { u16 u[4]; uint2 v; };

// ---------------- GroupNorm stats ----------------
__global__ __launch_bounds__(256) void k_gn_stats(const float* __restrict__ x,
                                                  float* __restrict__ mu, float* __restrict__ rs){
  int bg = blockIdx.x;
  const float4* p = (const float4*)(x + (size_t)bg * (8 * Nn));
  float s = 0.f, q = 0.f;
  for (int i = threadIdx.x; i < 8*Nn/4; i += 256){
    float4 v = p[i];
    s += v.x + v.y + v.z + v.w;
    q += v.x*v.x + v.y*v.y + v.z*v.z + v.w*v.w;
  }
  __shared__ float rsum[256], rsq[256];
  rsum[threadIdx.x] = s; rsq[threadIdx.x] = q;
  __syncthreads();
  for (int off = 128; off > 0; off >>= 1){
    if (threadIdx.x < off){ rsum[threadIdx.x] += rsum[threadIdx.x+off]; rsq[threadIdx.x] += rsq[threadIdx.x+off]; }
    __syncthreads();
  }
  if (threadIdx.x == 0){
    const float inv = 1.0f / (8*Nn);
    float m = rsum[0]*inv;
    float var = rsq[0]*inv - m*m;
    mu[bg] = m; rs[bg] = rsqrtf(var + 1e-6f);
  }
}

// ------------- GroupNorm apply + transpose -> hT hi/lo [b][n][c] -------------
__global__ __launch_bounds__(256) void k_gn_apply(const float* __restrict__ x,
                                                  const float* __restrict__ gsc, const float* __restrict__ gbi,
                                                  const float* __restrict__ mu, const float* __restrict__ rs,
                                                  u16* __restrict__ hhi, u16* __restrict__ hlo){
  int nt = blockIdx.x, ct = blockIdx.y, b = blockIdx.z;
  int n0 = nt*64, c0 = ct*64;
  __shared__ float yt[64*65];
  __shared__ float sa[64], sb[64];
  int t = threadIdx.x;
  if (t < 64){
    int c = c0 + t;
    int bg = b*NGRP + (c >> 3);
    float a = rs[bg] * gsc[c];
    sa[t] = a;
    sb[t] = gbi[c] - mu[bg]*a;
  }
  __syncthreads();
  #pragma unroll
  for (int j = 0; j < 4; ++j){
    int id = t + j*256;
    int r = id >> 4, cq = id & 15;
    float4 v = *(const float4*)(x + ((size_t)b*Cc + c0 + r)*Nn + n0 + cq*4);
    float a = sa[r], bb = sb[r];
    yt[r*65 + cq*4 + 0] = v.x*a + bb;
    yt[r*65 + cq*4 + 1] = v.y*a + bb;
    yt[r*65 + cq*4 + 2] = v.z*a + bb;
    yt[r*65 + cq*4 + 3] = v.w*a + bb;
  }
  __syncthreads();
  int nl = t >> 2, cg = (t & 3) * 16;
  size_t base = ((size_t)b*Nn + n0 + nl)*Cc + c0 + cg;
  #pragma unroll
  for (int half = 0; half < 2; ++half){
    union { u16 u[8]; uint4 v; } Ph, Pl;
    #pragma unroll
    for (int u = 0; u < 8; ++u){
      float y = yt[(cg + half*8 + u)*65 + nl];
      u16 h = f2bf(y);
      Ph.u[u] = h; Pl.u[u] = f2bf(y - bf2f(h));
    }
    *(uint4*)(hhi + base + half*8) = Ph.v;
    *(uint4*)(hlo + base + half*8) = Pl.v;
  }
}

// ------------- 1x1 conv GEMM (bf16 hi/lo, ~fp32 accurate) -------------
__global__ __launch_bounds__(256) void k_conv(const float* __restrict__ W,
                                              const u16* __restrict__ Hhi, const u16* __restrict__ Hlo,
                                              const float* __restrict__ bias,
                                              const float* __restrict__ pd, const float* __restrict__ pz,
                                              u8* __restrict__ outT, u8* __restrict__ outN,
                                              const float* __restrict__ xres, float* __restrict__ outF,
                                              int mode){
  int nt = blockIdx.x, ot = blockIdx.y, b = blockIdx.z;
  __shared__ u16 Lh[64*128], Ll[64*128];
  int t = threadIdx.x, lane = t & 63, wave = t >> 6;
  int lo16 = lane & 15, quad = lane >> 4;
  int o0 = ot*64 + wave*16;

  bf16x8 awh[8], awl[8];
  {
    const float* wb = W + (size_t)(o0 + lo16) * 256;
    #pragma unroll
    for (int k = 0; k < 8; ++k){
      union { u16 u[8]; bf16x8 v; } Wh, Wl;
      #pragma unroll
      for (int u = 0; u < 8; ++u){
        float w = wb[k*32 + quad*8 + u];
        u16 h = f2bf(w);
        Wh.u[u] = h; Wl.u[u] = f2bf(w - bf2f(h));
      }
      awh[k] = Wh.v; awl[k] = Wl.v;
    }
  }
  f32x4 zf = {0.f,0.f,0.f,0.f};
  f32x4 acc[4] = {zf, zf, zf, zf};

  const u16* hb = Hhi + ((size_t)b*Nn + nt*64) * 256;
  const u16* lb = Hlo + ((size_t)b*Nn + nt*64) * 256;
  for (int kc = 0; kc < 2; ++kc){
    __syncthreads();
    for (int id = t; id < 64*16; id += 256){
      int r = id >> 4, ch = id & 15;
      int sw = (ch ^ (r & 7)) * 8;
      *(uint4*)(Lh + r*128 + sw) = *(const uint4*)(hb + (size_t)r*256 + kc*128 + ch*8);
      *(uint4*)(Ll + r*128 + sw) = *(const uint4*)(lb + (size_t)r*256 + kc*128 + ch*8);
    }
    __syncthreads();
    #pragma unroll
    for (int k4 = 0; k4 < 4; ++k4){
      int k = kc*4 + k4;
      #pragma unroll
      for (int ns = 0; ns < 4; ++ns){
        int r = ns*16 + lo16;
        int ch = ((k4*4 + quad) ^ (r & 7)) * 8;
        bf16x8 bh = *(const bf16x8*)(Lh + r*128 + ch);
        bf16x8 bl = *(const bf16x8*)(Ll + r*128 + ch);
        acc[ns] = MFMA16(awh[k], bh, acc[ns]);
        acc[ns] = MFMA16(awl[k], bh, acc[ns]);
        acc[ns] = MFMA16(awh[k], bl, acc[ns]);
      }
    }
  }

  float bia[4];
  #pragma unroll
  for (int r = 0; r < 4; ++r) bia[r] = bias[o0 + quad*4 + r];

  if (mode == 0){
    float z = pz[0]; float invd = 1.0f / pd[0];
    #pragma unroll
    for (int ns = 0; ns < 4; ++ns){
      int n = nt*64 + ns*16 + lo16;
      u32 w = 0;
      #pragma unroll
      for (int r = 0; r < 4; ++r){
        float v = acc[ns][r] + bia[r];
        float xq = fminf(fmaxf(rintf(v*invd) + z, 0.f), 255.f);
        int qi = (int)rintf(xq - z);
        w |= ((u32)(qi & 255)) << (8*r);
      }
      *(u32*)(outT + ((size_t)b*Nn + n)*Cc + o0 + quad*4) = w;
    }
  } else if (mode == 1){
    float z = pz[0]; float invd = 1.0f / pd[0];
    #pragma unroll
    for (int ns = 0; ns < 4; ++ns){
      int n = nt*64 + ns*16 + lo16;
      #pragma unroll
      for (int r = 0; r < 4; ++r){
        float v = acc[ns][r] + bia[r];
        float xq = fminf(fmaxf(rintf(v*invd) + z, 0.f), 255.f);
        int qi = (int)rintf(xq - z);
        outN[((size_t)b*Cc + o0 + quad*4 + r)*Nn + n] = (u8)(qi & 255);
      }
    }
  } else {
    #pragma unroll
    for (int ns = 0; ns < 4; ++ns){
      int n = nt*64 + ns*16 + lo16;
      #pragma unroll
      for (int r = 0; r < 4; ++r){
        size_t a = ((size_t)b*Cc + o0 + quad*4 + r)*Nn + n;
        outF[a] = xres[a] + acc[ns][r] + bia[r];
      }
    }
  }
}

static __device__ __forceinline__ void stage64x256(u8* dst, const u8* __restrict__ src, int t){
  #pragma unroll
  for (int j = 0; j < 4; ++j){
    int id = t + j*256; int r = id >> 4, ch = id & 15;
    *(uint4*)(dst + r*256 + ((ch ^ (r & 15)) << 4)) = *(const uint4*)(src + r*256 + ch*16);
  }
}

// ------------- row norm^2 max: stat[0..3]=qmax2 per b, stat[4..7]=kmax2 -------------
static __device__ __forceinline__ int sq4(u32 w){
  int s = 0;
  #pragma unroll
  for (int j = 0; j < 4; ++j){ int v = (int)((signed char)((w >> (8*j)) & 0xffu)); s += v*v; }
  return s;
}
__global__ __launch_bounds__(256) void k_norms(const u8* __restrict__ qT8, const u8* __restrict__ kT8,
                                               u32* __restrict__ stat){
  int gid = blockIdx.x*256 + threadIdx.x;      // 0..32767
  int which = gid >> 14;                       // 0: q, 1: k
  int rid = gid & 16383;
  const u8* row = (which ? kT8 : qT8) + (size_t)rid * 256;
  int acc = 0;
  const uint4* p = (const uint4*)row;
  #pragma unroll
  for (int i = 0; i < 16; ++i){
    uint4 w = p[i];
    acc += sq4(w.x) + sq4(w.y) + sq4(w.z) + sq4(w.w);
  }
  atomicMax(&stat[which*4 + (rid >> 12)], (u32)acc);
}

// ------------- sum-exp pass: Lp[b][mc][n] = sum_{m in chunk} exp2(acc*sc2 - M2) -------------
__global__ __launch_bounds__(256) void k_sumexp(const u8* __restrict__ qT8, const u8* __restrict__ kT8,
                                                const u32* __restrict__ stat,
                                                const float* __restrict__ pdq, const float* __restrict__ pdk,
                                                float* __restrict__ Lp){
  int nt = blockIdx.x, mc = blockIdx.y, b = blockIdx.z;
  __shared__ u8 Kt[64*256];
  int t = threadIdx.x, lane = t & 63, wave = t >> 6;
  int lo16 = lane & 15, quad = lane >> 4;

  i32x4 a[4];
  {
    const u8* qb = qT8 + ((size_t)b*Nn + nt*64)*256;
    int ar = wave*16 + lo16;
    #pragma unroll
    for (int k = 0; k < 4; ++k)
      a[k] = *(const i32x4*)(qb + ar*256 + (k*4 + quad)*16);
  }
  float sc2 = pdq[0]*pdk[0]*0.0625f*LOG2E;
  float M2 = sc2 * sqrtf((float)stat[b] * (float)stat[4+b]);
  float lr[4] = {0.f,0.f,0.f,0.f};

  const u8* kbase = kT8 + ((size_t)b*Nn + mc*512)*256;
  for (int mt = 0; mt < 8; ++mt){
    __syncthreads();
    stage64x256(Kt, kbase + (size_t)mt*64*256, t);
    __syncthreads();
    #pragma unroll
    for (int ms = 0; ms < 4; ++ms){
      i32x4 acc = {0,0,0,0};
      int br = ms*16 + lo16;
      #pragma unroll
      for (int k = 0; k < 4; ++k){
        i32x4 bk_ = *(const i32x4*)(Kt + br*256 + (((k*4 + quad) ^ (br & 15)) << 4));
        acc = MFMA_I8(a[k], bk_, acc);
      }
      #pragma unroll
      for (int r = 0; r < 4; ++r)
        lr[r] += exp2f(fmaf((float)acc[r], sc2, -M2));
    }
  }
  #pragma unroll
  for (int msk = 1; msk < 16; msk <<= 1){
    #pragma unroll
    for (int r = 0; r < 4; ++r) lr[r] += __shfl_xor(lr[r], msk, 64);
  }
  if (lo16 == 0){
    #pragma unroll
    for (int r = 0; r < 4; ++r)
      Lp[((size_t)(b*8 + mc))*Nn + nt*64 + wave*16 + quad*4 + r] = lr[r];
  }
}

// ------------- reduce partial L -> invL -------------
__global__ __launch_bounds__(256) void k_redl(const float* __restrict__ Lp, float* __restrict__ invL){
  int gid = blockIdx.x*256 + threadIdx.x;      // b*Nn+n, 16384 total
  int b = gid >> 12, n = gid & 4095;
  float s = 0.f;
  #pragma unroll
  for (int mc = 0; mc < 8; ++mc) s += Lp[((size_t)(b*8 + mc))*Nn + n];
  invL[gid] = 1.0f / s;
}

// ------------- quant pass: aq[b][m][n] = (clip(round(attn/dw)+zw) ^ 0x80) -------------
__global__ __launch_bounds__(256) void k_quant(const u8* __restrict__ qT8, const u8* __restrict__ kT8,
                                               const u32* __restrict__ stat,
                                               const float* __restrict__ pdq, const float* __restrict__ pdk,
                                               const float* __restrict__ pdw, const float* __restrict__ pzw,
                                               const float* __restrict__ invL,
                                               u8* __restrict__ aq){
  int nt = blockIdx.x, mc = blockIdx.y, b = blockIdx.z;
  __shared__ u8 Kt[64*256];
  int t = threadIdx.x, lane = t & 63, wave = t >> 6;
  int lo16 = lane & 15, quad = lane >> 4;

  i32x4 a[4];
  {
    const u8* qb = qT8 + ((size_t)b*Nn + nt*64)*256;
    int ar = wave*16 + lo16;
    #pragma unroll
    for (int k = 0; k < 4; ++k)
      a[k] = *(const i32x4*)(qb + ar*256 + (k*4 + quad)*16);
  }
  float sc2 = pdq[0]*pdk[0]*0.0625f*LOG2E;
  float M2 = sc2 * sqrtf((float)stat[b] * (float)stat[4+b]);
  float invdw = 1.0f / pdw[0];
  float zw = pzw[0];
  int n0 = nt*64 + wave*16 + quad*4;
  float4 iv = *(const float4*)(invL + b*Nn + n0);
  float sr[4] = { iv.x*invdw, iv.y*invdw, iv.z*invdw, iv.w*invdw };

  u8* aqb = aq + (size_t)b*Nn*Nn + n0;
  const u8* kbase = kT8 + ((size_t)b*Nn + mc*512)*256;
  for (int mt = 0; mt < 8; ++mt){
    __syncthreads();
    stage64x256(Kt, kbase + (size_t)mt*64*256, t);
    __syncthreads();
    #pragma unroll
    for (int ms = 0; ms < 4; ++ms){
      i32x4 acc = {0,0,0,0};
      int br = ms*16 + lo16;
      #pragma unroll
      for (int k = 0; k < 4; ++k){
        i32x4 bk_ = *(const i32x4*)(Kt + br*256 + (((k*4 + quad) ^ (br & 15)) << 4));
        acc = MFMA_I8(a[k], bk_, acc);
      }
      int m = mc*512 + mt*64 + ms*16 + lo16;
      u32 w = 0;
      #pragma unroll
      for (int r = 0; r < 4; ++r){
        float at = exp2f(fmaf((float)acc[r], sc2, -M2)) * sr[r];
        float xq = fminf(fmaxf(rintf(at) + zw, 0.f), 255.f);
        w |= ((u32)(int)xq) << (8*r);
      }
      *(u32*)(aqb + (size_t)m*Nn) = w ^ 0x80808080u;
    }
  }
}

// ------------- PV GEMM (i8): h[c][n] = dv*dw*(sum V*(aq-128) + (128-zw)*sumV) -------------
__global__ __launch_bounds__(256) void k_pv(const u8* __restrict__ v8, const u8* __restrict__ aq,
                                            const float* __restrict__ pdv, const float* __restrict__ pdw,
                                            const float* __restrict__ pzw,
                                            u16* __restrict__ h2hi, u16* __restrict__ h2lo){
  int nt = blockIdx.x, ct = blockIdx.y, b = blockIdx.z;  // tile: 64 c x 128 n
  __shared__ u8 Vt[64*64];
  __shared__ u8 Pt[128*64];
  int t = threadIdx.x, lane = t & 63, wave = t >> 6;
  int lo16 = lane & 15, quad = lane >> 4;

  i32x4 zi = {0,0,0,0};
  i32x4 acc[8] = {zi,zi,zi,zi,zi,zi,zi,zi};
  i32x4 accO = zi;
  const i32x4 ones = {0x01010101,0x01010101,0x01010101,0x01010101};

  const u8* vbase = v8 + ((size_t)(b*Cc + ct*64))*Nn;
  const u8* abase = aq + (size_t)b*Nn*Nn + nt*128;
  int n4 = t & 31, mg = t >> 5;

  for (int mt = 0; mt < 64; ++mt){
    __syncthreads();
    {
      int c = t >> 2, ch = t & 3;
      *(uint4*)(Vt + c*64 + ((ch ^ (c & 3)) << 4)) = *(const uint4*)(vbase + (size_t)c*Nn + mt*64 + ch*16);
    }
    {
      u32 w[8];
      const u8* ab = abase + (size_t)(mt*64 + mg*8)*Nn + n4*4;
      #pragma unroll
      for (int j = 0; j < 8; ++j) w[j] = *(const u32*)(ab + (size_t)j*Nn);
      #pragma unroll
      for (int r = 0; r < 4; ++r){
        u32 sel = 0x0C0C0000u | ((u32)(4+r) << 8) | (u32)r;
        u32 x0 = __builtin_amdgcn_perm(w[1], w[0], sel);
        u32 y0 = __builtin_amdgcn_perm(w[3], w[2], sel);
        u32 lo = __builtin_amdgcn_perm(y0, x0, 0x05040100u);
        u32 x1 = __builtin_amdgcn_perm(w[5], w[4], sel);
        u32 y1 = __builtin_amdgcn_perm(w[7], w[6], sel);
        u32 hi = __builtin_amdgcn_perm(y1, x1, 0x05040100u);
        int n = n4*4 + r;
        u32* dst = (u32*)(Pt + n*64 + (((mg >> 1) ^ (n4 & 3)) << 4) + ((mg & 1) << 3));
        dst[0] = lo; dst[1] = hi;
      }
    }
    __syncthreads();
    int cr = wave*16 + lo16;
    i32x4 af = *(const i32x4*)(Vt + cr*64 + ((quad ^ (cr & 3)) << 4));
    accO = MFMA_I8(af, ones, accO);
    #pragma unroll
    for (int ns = 0; ns < 8; ++ns){
      int pr = ns*16 + lo16;
      i32x4 bf_ = *(const i32x4*)(Pt + pr*64 + ((quad ^ ((pr >> 2) & 3)) << 4));
      acc[ns] = MFMA_I8(af, bf_, acc[ns]);
    }
  }
  float s = pdv[0] * pdw[0];
  float corr = s * (128.0f - pzw[0]);
  #pragma unroll
  for (int ns = 0; ns < 8; ++ns){
    int n = nt*128 + ns*16 + lo16;
    int c0 = ct*64 + wave*16 + quad*4;
    U64c Uh, Ul;
    #pragma unroll
    for (int r = 0; r < 4; ++r){
      float val = s*(float)acc[ns][r] + corr*(float)accO[r];
      u16 h = f2bf(val);
      Uh.u[r] = h; Ul.u[r] = f2bf(val - bf2f(h));
    }
    *(uint2*)(h2hi + ((size_t)b*Nn + n)*Cc + c0) = Uh.v;
    *(uint2*)(h2lo + ((size_t)b*Nn + n)*Cc + c0) = Ul.v;
  }
}

extern "C" void kernel_launch(void* const* d_in, const int* in_sizes, int n_in,
                              void* d_out, int out_size, void* d_ws, size_t ws_size,
                              hipStream_t stream){
  (void)in_sizes; (void)n_in; (void)out_size; (void)ws_size;
  const float* x   = (const float*)d_in[0];
  const float* gsc = (const float*)d_in[1];
  const float* gbi = (const float*)d_in[2];
  const float* wq  = (const float*)d_in[3];
  const float* bq  = (const float*)d_in[4];
  const float* wk  = (const float*)d_in[5];
  const float* bk  = (const float*)d_in[6];
  const float* wv  = (const float*)d_in[7];
  const float* bv  = (const float*)d_in[8];
  const float* wp  = (const float*)d_in[9];
  const float* bp  = (const float*)d_in[10];
  const float* dq  = (const float*)d_in[11];
  const float* zq  = (const float*)d_in[12];
  const float* dk  = (const float*)d_in[13];
  const float* zk  = (const float*)d_in[14];
  const float* dv  = (const float*)d_in[15];
  const float* zv  = (const float*)d_in[16];
  const float* dw  = (const float*)d_in[17];
  const float* zw  = (const float*)d_in[18];
  float* out = (float*)d_out;

  const size_t SZT = (size_t)Bb*Nn*Cc;  // 4,194,304 elems
  u16* hT_hi = (u16*)d_ws;
  u16* hT_lo = hT_hi + SZT;
  u16* h2hi  = hT_lo + SZT;
  u16* h2lo  = h2hi + SZT;
  u8*  qT8   = (u8*)(h2lo + SZT);
  u8*  kT8   = qT8 + SZT;
  u8*  v8    = kT8 + SZT;
  u8*  aq    = v8 + SZT;
  float* mu  = (float*)(aq + (size_t)Bb*Nn*Nn);
  float* rs  = mu + 128;
  u32*  stat = (u32*)(rs + 128);
  float* Lp  = (float*)(stat + 8);
  float* invL= Lp + (size_t)Bb*8*Nn;
  // total ws use: ~109 MB

  k_gn_stats<<<dim3(Bb*NGRP), 256, 0, stream>>>(x, mu, rs);
  k_gn_apply<<<dim3(Nn/64, Cc/64, Bb), 256, 0, stream>>>(x, gsc, gbi, mu, rs, hT_hi, hT_lo);

  k_conv<<<dim3(Nn/64, 4, Bb), 256, 0, stream>>>(wq, hT_hi, hT_lo, bq, dq, zq, qT8, nullptr, nullptr, nullptr, 0);
  k_conv<<<dim3(Nn/64, 4, Bb), 256, 0, stream>>>(wk, hT_hi, hT_lo, bk, dk, zk, kT8, nullptr, nullptr, nullptr, 0);
  k_conv<<<dim3(Nn/64, 4, Bb), 256, 0, stream>>>(wv, hT_hi, hT_lo, bv, dv, zv, nullptr, v8, nullptr, nullptr, 1);

  hipMemsetAsync(stat, 0, 8*sizeof(u32), stream);
  k_norms<<<dim3(128), 256, 0, stream>>>(qT8, kT8, stat);
  k_sumexp<<<dim3(Nn/64, 8, Bb), 256, 0, stream>>>(qT8, kT8, stat, dq, dk, Lp);
  k_redl<<<dim3(Bb*Nn/256), 256, 0, stream>>>(Lp, invL);
  k_quant<<<dim3(Nn/64, 8, Bb), 256, 0, stream>>>(qT8, kT8, stat, dq, dk, dw, zw, invL, aq);

  k_pv<<<dim3(Nn/128, 4, Bb), 256, 0, stream>>>(v8, aq, dv, dw, zw, h2hi, h2lo);

  k_conv<<<dim3(Nn/64, 4, Bb), 256, 0, stream>>>(wp, h2hi, h2lo, bp, nullptr, nullptr, nullptr, nullptr, x, out, 2);
}

// Round 5
// 345.616 us; speedup vs baseline: 2.0621x; 2.0621x over previous
//
#include <hip/hip_runtime.h>

// QuantAttnBlock on gfx950, round 5: fix k_norms atomic contention
// (wave-reduce max, one atomicMax per wave instead of per thread).

#define Bb 4
#define Cc 256
#define Nn 4096
#define NGRP 32
#define LOG2E 1.4426950408889634f

typedef unsigned short u16;
typedef unsigned int   u32;
typedef unsigned char  u8;
typedef __attribute__((ext_vector_type(8))) short bf16x8;
typedef __attribute__((ext_vector_type(4))) float f32x4;
typedef __attribute__((ext_vector_type(4))) int   i32x4;

#define MFMA16(a,b,c)    __builtin_amdgcn_mfma_f32_16x16x32_bf16((a),(b),(c),0,0,0)
#define MFMA_I8(a,b,c)   __builtin_amdgcn_mfma_i32_16x16x64_i8((a),(b),(c),0,0,0)

static __device__ __forceinline__ u16 f2bf(float x){
  u32 u = __float_as_uint(x);
  u += 0x7fffu + ((u >> 16) & 1u);
  return (u16)(u >> 16);
}
static __device__ __forceinline__ float bf2f(u16 h){ return __uint_as_float(((u32)h) << 16); }

union U64c { u16 u[4]; uint2 v; };

// ---------------- GroupNorm stats ----------------
__global__ __launch_bounds__(256) void k_gn_stats(const float* __restrict__ x,
                                                  float* __restrict__ mu, float* __restrict__ rs){
  int bg = blockIdx.x;
  const float4* p = (const float4*)(x + (size_t)bg * (8 * Nn));
  float s = 0.f, q = 0.f;
  for (int i = threadIdx.x; i < 8*Nn/4; i += 256){
    float4 v = p[i];
    s += v.x + v.y + v.z + v.w;
    q += v.x*v.x + v.y*v.y + v.z*v.z + v.w*v.w;
  }
  __shared__ float rsum[256], rsq[256];
  rsum[threadIdx.x] = s; rsq[threadIdx.x] = q;
  __syncthreads();
  for (int off = 128; off > 0; off >>= 1){
    if (threadIdx.x < off){ rsum[threadIdx.x] += rsum[threadIdx.x+off]; rsq[threadIdx.x] += rsq[threadIdx.x+off]; }
    __syncthreads();
  }
  if (threadIdx.x == 0){
    const float inv = 1.0f / (8*Nn);
    float m = rsum[0]*inv;
    float var = rsq[0]*inv - m*m;
    mu[bg] = m; rs[bg] = rsqrtf(var + 1e-6f);
  }
}

// ------------- GroupNorm apply + transpose -> hT hi/lo [b][n][c] -------------
__global__ __launch_bounds__(256) void k_gn_apply(const float* __restrict__ x,
                                                  const float* __restrict__ gsc, const float* __restrict__ gbi,
                                                  const float* __restrict__ mu, const float* __restrict__ rs,
                                                  u16* __restrict__ hhi, u16* __restrict__ hlo){
  int nt = blockIdx.x, ct = blockIdx.y, b = blockIdx.z;
  int n0 = nt*64, c0 = ct*64;
  __shared__ float yt[64*65];
  __shared__ float sa[64], sb[64];
  int t = threadIdx.x;
  if (t < 64){
    int c = c0 + t;
    int bg = b*NGRP + (c >> 3);
    float a = rs[bg] * gsc[c];
    sa[t] = a;
    sb[t] = gbi[c] - mu[bg]*a;
  }
  __syncthreads();
  #pragma unroll
  for (int j = 0; j < 4; ++j){
    int id = t + j*256;
    int r = id >> 4, cq = id & 15;
    float4 v = *(const float4*)(x + ((size_t)b*Cc + c0 + r)*Nn + n0 + cq*4);
    float a = sa[r], bb = sb[r];
    yt[r*65 + cq*4 + 0] = v.x*a + bb;
    yt[r*65 + cq*4 + 1] = v.y*a + bb;
    yt[r*65 + cq*4 + 2] = v.z*a + bb;
    yt[r*65 + cq*4 + 3] = v.w*a + bb;
  }
  __syncthreads();
  int nl = t >> 2, cg = (t & 3) * 16;
  size_t base = ((size_t)b*Nn + n0 + nl)*Cc + c0 + cg;
  #pragma unroll
  for (int half = 0; half < 2; ++half){
    union { u16 u[8]; uint4 v; } Ph, Pl;
    #pragma unroll
    for (int u = 0; u < 8; ++u){
      float y = yt[(cg + half*8 + u)*65 + nl];
      u16 h = f2bf(y);
      Ph.u[u] = h; Pl.u[u] = f2bf(y - bf2f(h));
    }
    *(uint4*)(hhi + base + half*8) = Ph.v;
    *(uint4*)(hlo + base + half*8) = Pl.v;
  }
}

// ------------- 1x1 conv GEMM (bf16 hi/lo, ~fp32 accurate) -------------
__global__ __launch_bounds__(256) void k_conv(const float* __restrict__ W,
                                              const u16* __restrict__ Hhi, const u16* __restrict__ Hlo,
                                              const float* __restrict__ bias,
                                              const float* __restrict__ pd, const float* __restrict__ pz,
                                              u8* __restrict__ outT, u8* __restrict__ outN,
                                              const float* __restrict__ xres, float* __restrict__ outF,
                                              int mode){
  int nt = blockIdx.x, ot = blockIdx.y, b = blockIdx.z;
  __shared__ u16 Lh[64*128], Ll[64*128];
  int t = threadIdx.x, lane = t & 63, wave = t >> 6;
  int lo16 = lane & 15, quad = lane >> 4;
  int o0 = ot*64 + wave*16;

  bf16x8 awh[8], awl[8];
  {
    const float* wb = W + (size_t)(o0 + lo16) * 256;
    #pragma unroll
    for (int k = 0; k < 8; ++k){
      union { u16 u[8]; bf16x8 v; } Wh, Wl;
      #pragma unroll
      for (int u = 0; u < 8; ++u){
        float w = wb[k*32 + quad*8 + u];
        u16 h = f2bf(w);
        Wh.u[u] = h; Wl.u[u] = f2bf(w - bf2f(h));
      }
      awh[k] = Wh.v; awl[k] = Wl.v;
    }
  }
  f32x4 zf = {0.f,0.f,0.f,0.f};
  f32x4 acc[4] = {zf, zf, zf, zf};

  const u16* hb = Hhi + ((size_t)b*Nn + nt*64) * 256;
  const u16* lb = Hlo + ((size_t)b*Nn + nt*64) * 256;
  for (int kc = 0; kc < 2; ++kc){
    __syncthreads();
    for (int id = t; id < 64*16; id += 256){
      int r = id >> 4, ch = id & 15;
      int sw = (ch ^ (r & 7)) * 8;
      *(uint4*)(Lh + r*128 + sw) = *(const uint4*)(hb + (size_t)r*256 + kc*128 + ch*8);
      *(uint4*)(Ll + r*128 + sw) = *(const uint4*)(lb + (size_t)r*256 + kc*128 + ch*8);
    }
    __syncthreads();
    #pragma unroll
    for (int k4 = 0; k4 < 4; ++k4){
      int k = kc*4 + k4;
      #pragma unroll
      for (int ns = 0; ns < 4; ++ns){
        int r = ns*16 + lo16;
        int ch = ((k4*4 + quad) ^ (r & 7)) * 8;
        bf16x8 bh = *(const bf16x8*)(Lh + r*128 + ch);
        bf16x8 bl = *(const bf16x8*)(Ll + r*128 + ch);
        acc[ns] = MFMA16(awh[k], bh, acc[ns]);
        acc[ns] = MFMA16(awl[k], bh, acc[ns]);
        acc[ns] = MFMA16(awh[k], bl, acc[ns]);
      }
    }
  }

  float bia[4];
  #pragma unroll
  for (int r = 0; r < 4; ++r) bia[r] = bias[o0 + quad*4 + r];

  if (mode == 0){
    float z = pz[0]; float invd = 1.0f / pd[0];
    #pragma unroll
    for (int ns = 0; ns < 4; ++ns){
      int n = nt*64 + ns*16 + lo16;
      u32 w = 0;
      #pragma unroll
      for (int r = 0; r < 4; ++r){
        float v = acc[ns][r] + bia[r];
        float xq = fminf(fmaxf(rintf(v*invd) + z, 0.f), 255.f);
        int qi = (int)rintf(xq - z);
        w |= ((u32)(qi & 255)) << (8*r);
      }
      *(u32*)(outT + ((size_t)b*Nn + n)*Cc + o0 + quad*4) = w;
    }
  } else if (mode == 1){
    float z = pz[0]; float invd = 1.0f / pd[0];
    #pragma unroll
    for (int ns = 0; ns < 4; ++ns){
      int n = nt*64 + ns*16 + lo16;
      #pragma unroll
      for (int r = 0; r < 4; ++r){
        float v = acc[ns][r] + bia[r];
        float xq = fminf(fmaxf(rintf(v*invd) + z, 0.f), 255.f);
        int qi = (int)rintf(xq - z);
        outN[((size_t)b*Cc + o0 + quad*4 + r)*Nn + n] = (u8)(qi & 255);
      }
    }
  } else {
    #pragma unroll
    for (int ns = 0; ns < 4; ++ns){
      int n = nt*64 + ns*16 + lo16;
      #pragma unroll
      for (int r = 0; r < 4; ++r){
        size_t a = ((size_t)b*Cc + o0 + quad*4 + r)*Nn + n;
        outF[a] = xres[a] + acc[ns][r] + bia[r];
      }
    }
  }
}

static __device__ __forceinline__ void stage64x256(u8* dst, const u8* __restrict__ src, int t){
  #pragma unroll
  for (int j = 0; j < 4; ++j){
    int id = t + j*256; int r = id >> 4, ch = id & 15;
    *(uint4*)(dst + r*256 + ((ch ^ (r & 15)) << 4)) = *(const uint4*)(src + r*256 + ch*16);
  }
}

// ------------- row norm^2 max: stat[0..3]=qmax2 per b, stat[4..7]=kmax2 -------------
static __device__ __forceinline__ int sq4(u32 w){
  int s = 0;
  #pragma unroll
  for (int j = 0; j < 4; ++j){ int v = (int)((signed char)((w >> (8*j)) & 0xffu)); s += v*v; }
  return s;
}
__global__ __launch_bounds__(256) void k_norms(const u8* __restrict__ qT8, const u8* __restrict__ kT8,
                                               u32* __restrict__ stat){
  int gid = blockIdx.x*256 + threadIdx.x;      // 0..32767
  int which = gid >> 14;                       // 0: q, 1: k
  int rid = gid & 16383;
  const u8* row = (which ? kT8 : qT8) + (size_t)rid * 256;
  u32 acc = 0;
  const uint4* p = (const uint4*)row;
  #pragma unroll
  for (int i = 0; i < 16; ++i){
    uint4 w = p[i];
    acc += (u32)(sq4(w.x) + sq4(w.y) + sq4(w.z) + sq4(w.w));
  }
  // wave-level max (all lanes in a wave share the same (which, b))
  #pragma unroll
  for (int msk = 32; msk > 0; msk >>= 1){
    u32 o = (u32)__shfl_xor((int)acc, msk, 64);
    acc = acc > o ? acc : o;
  }
  if ((threadIdx.x & 63) == 0)
    atomicMax(&stat[which*4 + (rid >> 12)], acc);
}

// ------------- sum-exp pass: Lp[b][mc][n] = sum_{m in chunk} exp2(acc*sc2 - M2) -------------
__global__ __launch_bounds__(256) void k_sumexp(const u8* __restrict__ qT8, const u8* __restrict__ kT8,
                                                const u32* __restrict__ stat,
                                                const float* __restrict__ pdq, const float* __restrict__ pdk,
                                                float* __restrict__ Lp){
  int nt = blockIdx.x, mc = blockIdx.y, b = blockIdx.z;
  __shared__ u8 Kt[64*256];
  int t = threadIdx.x, lane = t & 63, wave = t >> 6;
  int lo16 = lane & 15, quad = lane >> 4;

  i32x4 a[4];
  {
    const u8* qb = qT8 + ((size_t)b*Nn + nt*64)*256;
    int ar = wave*16 + lo16;
    #pragma unroll
    for (int k = 0; k < 4; ++k)
      a[k] = *(const i32x4*)(qb + ar*256 + (k*4 + quad)*16);
  }
  float sc2 = pdq[0]*pdk[0]*0.0625f*LOG2E;
  float M2 = sc2 * sqrtf((float)stat[b] * (float)stat[4+b]);
  float lr[4] = {0.f,0.f,0.f,0.f};

  const u8* kbase = kT8 + ((size_t)b*Nn + mc*512)*256;
  for (int mt = 0; mt < 8; ++mt){
    __syncthreads();
    stage64x256(Kt, kbase + (size_t)mt*64*256, t);
    __syncthreads();
    #pragma unroll
    for (int ms = 0; ms < 4; ++ms){
      i32x4 acc = {0,0,0,0};
      int br = ms*16 + lo16;
      #pragma unroll
      for (int k = 0; k < 4; ++k){
        i32x4 bk_ = *(const i32x4*)(Kt + br*256 + (((k*4 + quad) ^ (br & 15)) << 4));
        acc = MFMA_I8(a[k], bk_, acc);
      }
      #pragma unroll
      for (int r = 0; r < 4; ++r)
        lr[r] += exp2f(fmaf((float)acc[r], sc2, -M2));
    }
  }
  #pragma unroll
  for (int msk = 1; msk < 16; msk <<= 1){
    #pragma unroll
    for (int r = 0; r < 4; ++r) lr[r] += __shfl_xor(lr[r], msk, 64);
  }
  if (lo16 == 0){
    #pragma unroll
    for (int r = 0; r < 4; ++r)
      Lp[((size_t)(b*8 + mc))*Nn + nt*64 + wave*16 + quad*4 + r] = lr[r];
  }
}

// ------------- reduce partial L -> invL -------------
__global__ __launch_bounds__(256) void k_redl(const float* __restrict__ Lp, float* __restrict__ invL){
  int gid = blockIdx.x*256 + threadIdx.x;      // b*Nn+n, 16384 total
  int b = gid >> 12, n = gid & 4095;
  float s = 0.f;
  #pragma unroll
  for (int mc = 0; mc < 8; ++mc) s += Lp[((size_t)(b*8 + mc))*Nn + n];
  invL[gid] = 1.0f / s;
}

// ------------- quant pass: aq[b][m][n] = (clip(round(attn/dw)+zw) ^ 0x80) -------------
__global__ __launch_bounds__(256) void k_quant(const u8* __restrict__ qT8, const u8* __restrict__ kT8,
                                               const u32* __restrict__ stat,
                                               const float* __restrict__ pdq, const float* __restrict__ pdk,
                                               const float* __restrict__ pdw, const float* __restrict__ pzw,
                                               const float* __restrict__ invL,
                                               u8* __restrict__ aq){
  int nt = blockIdx.x, mc = blockIdx.y, b = blockIdx.z;
  __shared__ u8 Kt[64*256];
  int t = threadIdx.x, lane = t & 63, wave = t >> 6;
  int lo16 = lane & 15, quad = lane >> 4;

  i32x4 a[4];
  {
    const u8* qb = qT8 + ((size_t)b*Nn + nt*64)*256;
    int ar = wave*16 + lo16;
    #pragma unroll
    for (int k = 0; k < 4; ++k)
      a[k] = *(const i32x4*)(qb + ar*256 + (k*4 + quad)*16);
  }
  float sc2 = pdq[0]*pdk[0]*0.0625f*LOG2E;
  float M2 = sc2 * sqrtf((float)stat[b] * (float)stat[4+b]);
  float invdw = 1.0f / pdw[0];
  float zw = pzw[0];
  int n0 = nt*64 + wave*16 + quad*4;
  float4 iv = *(const float4*)(invL + b*Nn + n0);
  float sr[4] = { iv.x*invdw, iv.y*invdw, iv.z*invdw, iv.w*invdw };

  u8* aqb = aq + (size_t)b*Nn*Nn + n0;
  const u8* kbase = kT8 + ((size_t)b*Nn + mc*512)*256;
  for (int mt = 0; mt < 8; ++mt){
    __syncthreads();
    stage64x256(Kt, kbase + (size_t)mt*64*256, t);
    __syncthreads();
    #pragma unroll
    for (int ms = 0; ms < 4; ++ms){
      i32x4 acc = {0,0,0,0};
      int br = ms*16 + lo16;
      #pragma unroll
      for (int k = 0; k < 4; ++k){
        i32x4 bk_ = *(const i32x4*)(Kt + br*256 + (((k*4 + quad) ^ (br & 15)) << 4));
        acc = MFMA_I8(a[k], bk_, acc);
      }
      int m = mc*512 + mt*64 + ms*16 + lo16;
      u32 w = 0;
      #pragma unroll
      for (int r = 0; r < 4; ++r){
        float at = exp2f(fmaf((float)acc[r], sc2, -M2)) * sr[r];
        float xq = fminf(fmaxf(rintf(at) + zw, 0.f), 255.f);
        w |= ((u32)(int)xq) << (8*r);
      }
      *(u32*)(aqb + (size_t)m*Nn) = w ^ 0x80808080u;
    }
  }
}

// ------------- PV GEMM (i8): h[c][n] = dv*dw*(sum V*(aq-128) + (128-zw)*sumV) -------------
__global__ __launch_bounds__(256) void k_pv(const u8* __restrict__ v8, const u8* __restrict__ aq,
                                            const float* __restrict__ pdv, const float* __restrict__ pdw,
                                            const float* __restrict__ pzw,
                                            u16* __restrict__ h2hi, u16* __restrict__ h2lo){
  int nt = blockIdx.x, ct = blockIdx.y, b = blockIdx.z;  // tile: 64 c x 128 n
  __shared__ u8 Vt[64*64];
  __shared__ u8 Pt[128*64];
  int t = threadIdx.x, lane = t & 63, wave = t >> 6;
  int lo16 = lane & 15, quad = lane >> 4;

  i32x4 zi = {0,0,0,0};
  i32x4 acc[8] = {zi,zi,zi,zi,zi,zi,zi,zi};
  i32x4 accO = zi;
  const i32x4 ones = {0x01010101,0x01010101,0x01010101,0x01010101};

  const u8* vbase = v8 + ((size_t)(b*Cc + ct*64))*Nn;
  const u8* abase = aq + (size_t)b*Nn*Nn + nt*128;
  int n4 = t & 31, mg = t >> 5;

  for (int mt = 0; mt < 64; ++mt){
    __syncthreads();
    {
      int c = t >> 2, ch = t & 3;
      *(uint4*)(Vt + c*64 + ((ch ^ (c & 3)) << 4)) = *(const uint4*)(vbase + (size_t)c*Nn + mt*64 + ch*16);
    }
    {
      u32 w[8];
      const u8* ab = abase + (size_t)(mt*64 + mg*8)*Nn + n4*4;
      #pragma unroll
      for (int j = 0; j < 8; ++j) w[j] = *(const u32*)(ab + (size_t)j*Nn);
      #pragma unroll
      for (int r = 0; r < 4; ++r){
        u32 sel = 0x0C0C0000u | ((u32)(4+r) << 8) | (u32)r;
        u32 x0 = __builtin_amdgcn_perm(w[1], w[0], sel);
        u32 y0 = __builtin_amdgcn_perm(w[3], w[2], sel);
        u32 lo = __builtin_amdgcn_perm(y0, x0, 0x05040100u);
        u32 x1 = __builtin_amdgcn_perm(w[5], w[4], sel);
        u32 y1 = __builtin_amdgcn_perm(w[7], w[6], sel);
        u32 hi = __builtin_amdgcn_perm(y1, x1, 0x05040100u);
        int n = n4*4 + r;
        u32* dst = (u32*)(Pt + n*64 + (((mg >> 1) ^ (n4 & 3)) << 4) + ((mg & 1) << 3));
        dst[0] = lo; dst[1] = hi;
      }
    }
    __syncthreads();
    int cr = wave*16 + lo16;
    i32x4 af = *(const i32x4*)(Vt + cr*64 + ((quad ^ (cr & 3)) << 4));
    accO = MFMA_I8(af, ones, accO);
    #pragma unroll
    for (int ns = 0; ns < 8; ++ns){
      int pr = ns*16 + lo16;
      i32x4 bf_ = *(const i32x4*)(Pt + pr*64 + ((quad ^ ((pr >> 2) & 3)) << 4));
      acc[ns] = MFMA_I8(af, bf_, acc[ns]);
    }
  }
  float s = pdv[0] * pdw[0];
  float corr = s * (128.0f - pzw[0]);
  #pragma unroll
  for (int ns = 0; ns < 8; ++ns){
    int n = nt*128 + ns*16 + lo16;
    int c0 = ct*64 + wave*16 + quad*4;
    U64c Uh, Ul;
    #pragma unroll
    for (int r = 0; r < 4; ++r){
      float val = s*(float)acc[ns][r] + corr*(float)accO[r];
      u16 h = f2bf(val);
      Uh.u[r] = h; Ul.u[r] = f2bf(val - bf2f(h));
    }
    *(uint2*)(h2hi + ((size_t)b*Nn + n)*Cc + c0) = Uh.v;
    *(uint2*)(h2lo + ((size_t)b*Nn + n)*Cc + c0) = Ul.v;
  }
}

extern "C" void kernel_launch(void* const* d_in, const int* in_sizes, int n_in,
                              void* d_out, int out_size, void* d_ws, size_t ws_size,
                              hipStream_t stream){
  (void)in_sizes; (void)n_in; (void)out_size; (void)ws_size;
  const float* x   = (const float*)d_in[0];
  const float* gsc = (const float*)d_in[1];
  const float* gbi = (const float*)d_in[2];
  const float* wq  = (const float*)d_in[3];
  const float* bq  = (const float*)d_in[4];
  const float* wk  = (const float*)d_in[5];
  const float* bk  = (const float*)d_in[6];
  const float* wv  = (const float*)d_in[7];
  const float* bv  = (const float*)d_in[8];
  const float* wp  = (const float*)d_in[9];
  const float* bp  = (const float*)d_in[10];
  const float* dq  = (const float*)d_in[11];
  const float* zq  = (const float*)d_in[12];
  const float* dk  = (const float*)d_in[13];
  const float* zk  = (const float*)d_in[14];
  const float* dv  = (const float*)d_in[15];
  const float* zv  = (const float*)d_in[16];
  const float* dw  = (const float*)d_in[17];
  const float* zw  = (const float*)d_in[18];
  float* out = (float*)d_out;

  const size_t SZT = (size_t)Bb*Nn*Cc;  // 4,194,304 elems
  u16* hT_hi = (u16*)d_ws;
  u16* hT_lo = hT_hi + SZT;
  u16* h2hi  = hT_lo + SZT;
  u16* h2lo  = h2hi + SZT;
  u8*  qT8   = (u8*)(h2lo + SZT);
  u8*  kT8   = qT8 + SZT;
  u8*  v8    = kT8 + SZT;
  u8*  aq    = v8 + SZT;
  float* mu  = (float*)(aq + (size_t)Bb*Nn*Nn);
  float* rs  = mu + 128;
  u32*  stat = (u32*)(rs + 128);
  float* Lp  = (float*)(stat + 8);
  float* invL= Lp + (size_t)Bb*8*Nn;
  // total ws use: ~109 MB

  k_gn_stats<<<dim3(Bb*NGRP), 256, 0, stream>>>(x, mu, rs);
  k_gn_apply<<<dim3(Nn/64, Cc/64, Bb), 256, 0, stream>>>(x, gsc, gbi, mu, rs, hT_hi, hT_lo);

  k_conv<<<dim3(Nn/64, 4, Bb), 256, 0, stream>>>(wq, hT_hi, hT_lo, bq, dq, zq, qT8, nullptr, nullptr, nullptr, 0);
  k_conv<<<dim3(Nn/64, 4, Bb), 256, 0, stream>>>(wk, hT_hi, hT_lo, bk, dk, zk, kT8, nullptr, nullptr, nullptr, 0);
  k_conv<<<dim3(Nn/64, 4, Bb), 256, 0, stream>>>(wv, hT_hi, hT_lo, bv, dv, zv, nullptr, v8, nullptr, nullptr, 1);

  hipMemsetAsync(stat, 0, 8*sizeof(u32), stream);
  k_norms<<<dim3(128), 256, 0, stream>>>(qT8, kT8, stat);
  k_sumexp<<<dim3(Nn/64, 8, Bb), 256, 0, stream>>>(qT8, kT8, stat, dq, dk, Lp);
  k_redl<<<dim3(Bb*Nn/256), 256, 0, stream>>>(Lp, invL);
  k_quant<<<dim3(Nn/64, 8, Bb), 256, 0, stream>>>(qT8, kT8, stat, dq, dk, dw, zw, invL, aq);

  k_pv<<<dim3(Nn/128, 4, Bb), 256, 0, stream>>>(v8, aq, dv, dw, zw, h2hi, h2lo);

  k_conv<<<dim3(Nn/64, 4, Bb), 256, 0, stream>>>(wp, h2hi, h2lo, bp, nullptr, nullptr, nullptr, nullptr, x, out, 2);
}

// Round 6
// 299.482 us; speedup vs baseline: 2.3798x; 1.1540x over previous
//
#include <hip/hip_runtime.h>

// QuantAttnBlock on gfx950, round 6:
//  - aq stored in A-fragment-ready blocked layout [b][m/16][n][16]; transpose
//    moved into k_quant via conflict-free LDS (done once, not 4x).
//  - k_pv rewritten lean: no perms, direct blocked loads, dbuf staging,
//    1 barrier/m-tile, vsum precomputed.
//  - q/k/v convs fused (H staged once).

#define Bb 4
#define Cc 256
#define Nn 4096
#define NGRP 32
#define LOG2E 1.4426950408889634f

typedef unsigned short u16;
typedef unsigned int   u32;
typedef unsigned char  u8;
typedef __attribute__((ext_vector_type(8))) short bf16x8;
typedef __attribute__((ext_vector_type(4))) float f32x4;
typedef __attribute__((ext_vector_type(4))) int   i32x4;

#define MFMA16(a,b,c)    __builtin_amdgcn_mfma_f32_16x16x32_bf16((a),(b),(c),0,0,0)
#define MFMA_I8(a,b,c)   __builtin_amdgcn_mfma_i32_16x16x64_i8((a),(b),(c),0,0,0)

static __device__ __forceinline__ u16 f2bf(float x){
  u32 u = __float_as_uint(x);
  u += 0x7fffu + ((u >> 16) & 1u);
  return (u16)(u >> 16);
}
static __device__ __forceinline__ float bf2f(u16 h){ return __uint_as_float(((u32)h) << 16); }

union U64c { u16 u[4]; uint2 v; };

// ---------------- GroupNorm stats ----------------
__global__ __launch_bounds__(256) void k_gn_stats(const float* __restrict__ x,
                                                  float* __restrict__ mu, float* __restrict__ rs){
  int bg = blockIdx.x;
  const float4* p = (const float4*)(x + (size_t)bg * (8 * Nn));
  float s = 0.f, q = 0.f;
  for (int i = threadIdx.x; i < 8*Nn/4; i += 256){
    float4 v = p[i];
    s += v.x + v.y + v.z + v.w;
    q += v.x*v.x + v.y*v.y + v.z*v.z + v.w*v.w;
  }
  __shared__ float rsum[256], rsq[256];
  rsum[threadIdx.x] = s; rsq[threadIdx.x] = q;
  __syncthreads();
  for (int off = 128; off > 0; off >>= 1){
    if (threadIdx.x < off){ rsum[threadIdx.x] += rsum[threadIdx.x+off]; rsq[threadIdx.x] += rsq[threadIdx.x+off]; }
    __syncthreads();
  }
  if (threadIdx.x == 0){
    const float inv = 1.0f / (8*Nn);
    float m = rsum[0]*inv;
    float var = rsq[0]*inv - m*m;
    mu[bg] = m; rs[bg] = rsqrtf(var + 1e-6f);
  }
}

// ------------- GroupNorm apply + transpose -> hT hi/lo [b][n][c] -------------
__global__ __launch_bounds__(256) void k_gn_apply(const float* __restrict__ x,
                                                  const float* __restrict__ gsc, const float* __restrict__ gbi,
                                                  const float* __restrict__ mu, const float* __restrict__ rs,
                                                  u16* __restrict__ hhi, u16* __restrict__ hlo){
  int nt = blockIdx.x, ct = blockIdx.y, b = blockIdx.z;
  int n0 = nt*64, c0 = ct*64;
  __shared__ float yt[64*65];
  __shared__ float sa[64], sb[64];
  int t = threadIdx.x;
  if (t < 64){
    int c = c0 + t;
    int bg = b*NGRP + (c >> 3);
    float a = rs[bg] * gsc[c];
    sa[t] = a;
    sb[t] = gbi[c] - mu[bg]*a;
  }
  __syncthreads();
  #pragma unroll
  for (int j = 0; j < 4; ++j){
    int id = t + j*256;
    int r = id >> 4, cq = id & 15;
    float4 v = *(const float4*)(x + ((size_t)b*Cc + c0 + r)*Nn + n0 + cq*4);
    float a = sa[r], bb = sb[r];
    yt[r*65 + cq*4 + 0] = v.x*a + bb;
    yt[r*65 + cq*4 + 1] = v.y*a + bb;
    yt[r*65 + cq*4 + 2] = v.z*a + bb;
    yt[r*65 + cq*4 + 3] = v.w*a + bb;
  }
  __syncthreads();
  int nl = t >> 2, cg = (t & 3) * 16;
  size_t base = ((size_t)b*Nn + n0 + nl)*Cc + c0 + cg;
  #pragma unroll
  for (int half = 0; half < 2; ++half){
    union { u16 u[8]; uint4 v; } Ph, Pl;
    #pragma unroll
    for (int u = 0; u < 8; ++u){
      float y = yt[(cg + half*8 + u)*65 + nl];
      u16 h = f2bf(y);
      Ph.u[u] = h; Pl.u[u] = f2bf(y - bf2f(h));
    }
    *(uint4*)(hhi + base + half*8) = Ph.v;
    *(uint4*)(hlo + base + half*8) = Pl.v;
  }
}

// ------------- Fused QKV conv GEMM (bf16 hi/lo, ~fp32 accurate) -------------
// Stages the 64n x 256c H tile once (64 KB LDS), loops the 3 weight sets.
// q,k: fake-quant -> i8, store [b][n][c]. v: fake-quant -> i8, store [b][c][m].
__global__ __launch_bounds__(256) void k_convqkv(const float* __restrict__ Wq,
                                                 const float* __restrict__ Wk,
                                                 const float* __restrict__ Wv,
                                                 const u16* __restrict__ Hhi, const u16* __restrict__ Hlo,
                                                 const float* __restrict__ bq, const float* __restrict__ bk,
                                                 const float* __restrict__ bv,
                                                 const float* __restrict__ dq, const float* __restrict__ zq,
                                                 const float* __restrict__ dk, const float* __restrict__ zk,
                                                 const float* __restrict__ dv, const float* __restrict__ zv,
                                                 u8* __restrict__ qT8, u8* __restrict__ kT8,
                                                 u8* __restrict__ v8){
  int nt = blockIdx.x, ot = blockIdx.y, b = blockIdx.z;
  __shared__ u16 Lh[64*256], Ll[64*256];
  int t = threadIdx.x, lane = t & 63, wave = t >> 6;
  int lo16 = lane & 15, quad = lane >> 4;
  int o0 = ot*64 + wave*16;

  {
    const u16* hb = Hhi + ((size_t)b*Nn + nt*64) * 256;
    const u16* lb = Hlo + ((size_t)b*Nn + nt*64) * 256;
    #pragma unroll
    for (int j = 0; j < 8; ++j){
      int id = t + j*256;
      int r = id >> 5, ch = id & 31;
      int sw = (ch ^ (r & 15)) * 8;
      *(uint4*)(Lh + r*256 + sw) = *(const uint4*)(hb + (size_t)r*256 + ch*8);
      *(uint4*)(Ll + r*256 + sw) = *(const uint4*)(lb + (size_t)r*256 + ch*8);
    }
  }
  __syncthreads();

  const float* Ws[3] = {Wq, Wk, Wv};
  const float* Bs[3] = {bq, bk, bv};
  const float* Dsr[3] = {dq, dk, dv};
  const float* Zs[3] = {zq, zk, zv};

  #pragma unroll
  for (int ws = 0; ws < 3; ++ws){
    bf16x8 awh[8], awl[8];
    {
      const float* wb = Ws[ws] + (size_t)(o0 + lo16) * 256;
      #pragma unroll
      for (int k = 0; k < 8; ++k){
        union { u16 u[8]; bf16x8 v; } Wh, Wl;
        #pragma unroll
        for (int u = 0; u < 8; ++u){
          float w = wb[k*32 + quad*8 + u];
          u16 h = f2bf(w);
          Wh.u[u] = h; Wl.u[u] = f2bf(w - bf2f(h));
        }
        awh[k] = Wh.v; awl[k] = Wl.v;
      }
    }
    f32x4 zf = {0.f,0.f,0.f,0.f};
    f32x4 acc[4] = {zf, zf, zf, zf};
    #pragma unroll
    for (int k = 0; k < 8; ++k){
      #pragma unroll
      for (int ns = 0; ns < 4; ++ns){
        int r = ns*16 + lo16;
        int ph = ((k*4 + quad) ^ (r & 15)) * 8;
        bf16x8 bh = *(const bf16x8*)(Lh + r*256 + ph);
        bf16x8 bl = *(const bf16x8*)(Ll + r*256 + ph);
        acc[ns] = MFMA16(awh[k], bh, acc[ns]);
        acc[ns] = MFMA16(awl[k], bh, acc[ns]);
        acc[ns] = MFMA16(awh[k], bl, acc[ns]);
      }
    }
    float bia[4];
    #pragma unroll
    for (int r = 0; r < 4; ++r) bia[r] = Bs[ws][o0 + quad*4 + r];
    float z = Zs[ws][0]; float invd = 1.0f / Dsr[ws][0];

    if (ws < 2){
      u8* outT = (ws == 0) ? qT8 : kT8;
      #pragma unroll
      for (int ns = 0; ns < 4; ++ns){
        int n = nt*64 + ns*16 + lo16;
        u32 w = 0;
        #pragma unroll
        for (int r = 0; r < 4; ++r){
          float v = acc[ns][r] + bia[r];
          float xq = fminf(fmaxf(rintf(v*invd) + z, 0.f), 255.f);
          int qi = (int)rintf(xq - z);
          w |= ((u32)(qi & 255)) << (8*r);
        }
        *(u32*)(outT + ((size_t)b*Nn + n)*Cc + o0 + quad*4) = w;
      }
    } else {
      #pragma unroll
      for (int ns = 0; ns < 4; ++ns){
        int n = nt*64 + ns*16 + lo16;
        #pragma unroll
        for (int r = 0; r < 4; ++r){
          float v = acc[ns][r] + bia[r];
          float xq = fminf(fmaxf(rintf(v*invd) + z, 0.f), 255.f);
          int qi = (int)rintf(xq - z);
          v8[((size_t)b*Cc + o0 + quad*4 + r)*Nn + n] = (u8)(qi & 255);
        }
      }
    }
  }
}

// ------------- proj conv (bf16 hi/lo) + residual -> f32 out -------------
__global__ __launch_bounds__(256) void k_conv(const float* __restrict__ W,
                                              const u16* __restrict__ Hhi, const u16* __restrict__ Hlo,
                                              const float* __restrict__ bias,
                                              const float* __restrict__ xres, float* __restrict__ outF){
  int nt = blockIdx.x, ot = blockIdx.y, b = blockIdx.z;
  __shared__ u16 Lh[64*128], Ll[64*128];
  int t = threadIdx.x, lane = t & 63, wave = t >> 6;
  int lo16 = lane & 15, quad = lane >> 4;
  int o0 = ot*64 + wave*16;

  bf16x8 awh[8], awl[8];
  {
    const float* wb = W + (size_t)(o0 + lo16) * 256;
    #pragma unroll
    for (int k = 0; k < 8; ++k){
      union { u16 u[8]; bf16x8 v; } Wh, Wl;
      #pragma unroll
      for (int u = 0; u < 8; ++u){
        float w = wb[k*32 + quad*8 + u];
        u16 h = f2bf(w);
        Wh.u[u] = h; Wl.u[u] = f2bf(w - bf2f(h));
      }
      awh[k] = Wh.v; awl[k] = Wl.v;
    }
  }
  f32x4 zf = {0.f,0.f,0.f,0.f};
  f32x4 acc[4] = {zf, zf, zf, zf};

  const u16* hb = Hhi + ((size_t)b*Nn + nt*64) * 256;
  const u16* lb = Hlo + ((size_t)b*Nn + nt*64) * 256;
  for (int kc = 0; kc < 2; ++kc){
    __syncthreads();
    for (int id = t; id < 64*16; id += 256){
      int r = id >> 4, ch = id & 15;
      int sw = (ch ^ (r & 7)) * 8;
      *(uint4*)(Lh + r*128 + sw) = *(const uint4*)(hb + (size_t)r*256 + kc*128 + ch*8);
      *(uint4*)(Ll + r*128 + sw) = *(const uint4*)(lb + (size_t)r*256 + kc*128 + ch*8);
    }
    __syncthreads();
    #pragma unroll
    for (int k4 = 0; k4 < 4; ++k4){
      int k = kc*4 + k4;
      #pragma unroll
      for (int ns = 0; ns < 4; ++ns){
        int r = ns*16 + lo16;
        int ch = ((k4*4 + quad) ^ (r & 7)) * 8;
        bf16x8 bh = *(const bf16x8*)(Lh + r*128 + ch);
        bf16x8 bl = *(const bf16x8*)(Ll + r*128 + ch);
        acc[ns] = MFMA16(awh[k], bh, acc[ns]);
        acc[ns] = MFMA16(awl[k], bh, acc[ns]);
        acc[ns] = MFMA16(awh[k], bl, acc[ns]);
      }
    }
  }

  float bia[4];
  #pragma unroll
  for (int r = 0; r < 4; ++r) bia[r] = bias[o0 + quad*4 + r];
  #pragma unroll
  for (int ns = 0; ns < 4; ++ns){
    int n = nt*64 + ns*16 + lo16;
    #pragma unroll
    for (int r = 0; r < 4; ++r){
      size_t a = ((size_t)b*Cc + o0 + quad*4 + r)*Nn + n;
      outF[a] = xres[a] + acc[ns][r] + bia[r];
    }
  }
}

static __device__ __forceinline__ void stage64x256(u8* dst, const u8* __restrict__ src, int t){
  #pragma unroll
  for (int j = 0; j < 4; ++j){
    int id = t + j*256; int r = id >> 4, ch = id & 15;
    *(uint4*)(dst + r*256 + ((ch ^ (r & 15)) << 4)) = *(const uint4*)(src + r*256 + ch*16);
  }
}

// ------------- row norm^2 max -------------
static __device__ __forceinline__ int sq4(u32 w){
  int s = 0;
  #pragma unroll
  for (int j = 0; j < 4; ++j){ int v = (int)((signed char)((w >> (8*j)) & 0xffu)); s += v*v; }
  return s;
}
__global__ __launch_bounds__(256) void k_norms(const u8* __restrict__ qT8, const u8* __restrict__ kT8,
                                               u32* __restrict__ stat){
  int gid = blockIdx.x*256 + threadIdx.x;
  int which = gid >> 14;
  int rid = gid & 16383;
  const u8* row = (which ? kT8 : qT8) + (size_t)rid * 256;
  u32 acc = 0;
  const uint4* p = (const uint4*)row;
  #pragma unroll
  for (int i = 0; i < 16; ++i){
    uint4 w = p[i];
    acc += (u32)(sq4(w.x) + sq4(w.y) + sq4(w.z) + sq4(w.w));
  }
  #pragma unroll
  for (int msk = 32; msk > 0; msk >>= 1){
    u32 o = (u32)__shfl_xor((int)acc, msk, 64);
    acc = acc > o ? acc : o;
  }
  if ((threadIdx.x & 63) == 0)
    atomicMax(&stat[which*4 + (rid >> 12)], acc);
}

// ------------- vsum[b*Cc+c] = sum_m signed(v8[c][m]) -------------
static __device__ __forceinline__ int ssum4(u32 w){
  return ((int)(w << 24) >> 24) + ((int)(w << 16) >> 24) + ((int)(w << 8) >> 24) + ((int)w >> 24);
}
__global__ __launch_bounds__(256) void k_vsum(const u8* __restrict__ v8, int* __restrict__ vsum){
  int row = blockIdx.x;                        // b*Cc + c, 1024 rows
  uint4 w = *(const uint4*)(v8 + (size_t)row*Nn + threadIdx.x*16);
  int s = ssum4(w.x) + ssum4(w.y) + ssum4(w.z) + ssum4(w.w);
  #pragma unroll
  for (int msk = 1; msk < 64; msk <<= 1) s += __shfl_xor(s, msk, 64);
  __shared__ int r4[4];
  if ((threadIdx.x & 63) == 0) r4[threadIdx.x >> 6] = s;
  __syncthreads();
  if (threadIdx.x == 0) vsum[row] = r4[0] + r4[1] + r4[2] + r4[3];
}

// ------------- sum-exp pass -------------
__global__ __launch_bounds__(256) void k_sumexp(const u8* __restrict__ qT8, const u8* __restrict__ kT8,
                                                const u32* __restrict__ stat,
                                                const float* __restrict__ pdq, const float* __restrict__ pdk,
                                                float* __restrict__ Lp){
  int nt = blockIdx.x, mc = blockIdx.y, b = blockIdx.z;
  __shared__ u8 Kt[64*256];
  int t = threadIdx.x, lane = t & 63, wave = t >> 6;
  int lo16 = lane & 15, quad = lane >> 4;

  i32x4 a[4];
  {
    const u8* qb = qT8 + ((size_t)b*Nn + nt*64)*256;
    int ar = wave*16 + lo16;
    #pragma unroll
    for (int k = 0; k < 4; ++k)
      a[k] = *(const i32x4*)(qb + ar*256 + (k*4 + quad)*16);
  }
  float sc2 = pdq[0]*pdk[0]*0.0625f*LOG2E;
  float M2 = sc2 * sqrtf((float)stat[b] * (float)stat[4+b]);
  float lr[4] = {0.f,0.f,0.f,0.f};

  const u8* kbase = kT8 + ((size_t)b*Nn + mc*512)*256;
  for (int mt = 0; mt < 8; ++mt){
    __syncthreads();
    stage64x256(Kt, kbase + (size_t)mt*64*256, t);
    __syncthreads();
    #pragma unroll
    for (int ms = 0; ms < 4; ++ms){
      i32x4 acc = {0,0,0,0};
      int br = ms*16 + lo16;
      #pragma unroll
      for (int k = 0; k < 4; ++k){
        i32x4 bk_ = *(const i32x4*)(Kt + br*256 + (((k*4 + quad) ^ (br & 15)) << 4));
        acc = MFMA_I8(a[k], bk_, acc);
      }
      #pragma unroll
      for (int r = 0; r < 4; ++r)
        lr[r] += exp2f(fmaf((float)acc[r], sc2, -M2));
    }
  }
  #pragma unroll
  for (int msk = 1; msk < 16; msk <<= 1){
    #pragma unroll
    for (int r = 0; r < 4; ++r) lr[r] += __shfl_xor(lr[r], msk, 64);
  }
  if (lo16 == 0){
    #pragma unroll
    for (int r = 0; r < 4; ++r)
      Lp[((size_t)(b*8 + mc))*Nn + nt*64 + wave*16 + quad*4 + r] = lr[r];
  }
}

// ------------- reduce partial L -> invL -------------
__global__ __launch_bounds__(256) void k_redl(const float* __restrict__ Lp, float* __restrict__ invL){
  int gid = blockIdx.x*256 + threadIdx.x;
  int b = gid >> 12, n = gid & 4095;
  float s = 0.f;
  #pragma unroll
  for (int mc = 0; mc < 8; ++mc) s += Lp[((size_t)(b*8 + mc))*Nn + n];
  invL[gid] = 1.0f / s;
}

// ------------- quant pass: compute attn^T, quantize, transpose in LDS,
// store aqB blocked [b][m/16][n][16] (bytes ^0x80) -------------
__global__ __launch_bounds__(256) void k_quant(const u8* __restrict__ qT8, const u8* __restrict__ kT8,
                                               const u32* __restrict__ stat,
                                               const float* __restrict__ pdq, const float* __restrict__ pdk,
                                               const float* __restrict__ pdw, const float* __restrict__ pzw,
                                               const float* __restrict__ invL,
                                               u8* __restrict__ aqB){
  int nt = blockIdx.x, mc = blockIdx.y, b = blockIdx.z;
  __shared__ u8 Kt[64*256];
  __shared__ u32 Wb[64*16];
  int t = threadIdx.x, lane = t & 63, wave = t >> 6;
  int lo16 = lane & 15, quad = lane >> 4;

  i32x4 a[4];
  {
    const u8* qb = qT8 + ((size_t)b*Nn + nt*64)*256;
    int ar = wave*16 + lo16;
    #pragma unroll
    for (int k = 0; k < 4; ++k)
      a[k] = *(const i32x4*)(qb + ar*256 + (k*4 + quad)*16);
  }
  float sc2 = pdq[0]*pdk[0]*0.0625f*LOG2E;
  float M2 = sc2 * sqrtf((float)stat[b] * (float)stat[4+b]);
  float invdw = 1.0f / pdw[0];
  float zw = pzw[0];
  int n0 = nt*64 + wave*16 + quad*4;
  float4 iv = *(const float4*)(invL + b*Nn + n0);
  float sr[4] = { iv.x*invdw, iv.y*invdw, iv.z*invdw, iv.w*invdw };
  u32 bsel = (u32)(lane & 3);
  u32 sel1 = 0x0C0C0000u | ((4u + bsel) << 8) | bsel;

  const u8* kbase = kT8 + ((size_t)b*Nn + mc*512)*256;
  for (int mt = 0; mt < 8; ++mt){
    __syncthreads();
    stage64x256(Kt, kbase + (size_t)mt*64*256, t);
    __syncthreads();
    #pragma unroll
    for (int ms = 0; ms < 4; ++ms){
      i32x4 acc = {0,0,0,0};
      int br = ms*16 + lo16;
      #pragma unroll
      for (int k = 0; k < 4; ++k){
        i32x4 bk_ = *(const i32x4*)(Kt + br*256 + (((k*4 + quad) ^ (br & 15)) << 4));
        acc = MFMA_I8(a[k], bk_, acc);
      }
      u32 w = 0;
      #pragma unroll
      for (int r = 0; r < 4; ++r){
        float at = exp2f(fmaf((float)acc[r], sc2, -M2)) * sr[r];
        float xq = fminf(fmaxf(rintf(at) + zw, 0.f), 255.f);
        w |= ((u32)(int)xq) << (8*r);
      }
      // LDS transpose buffer: row = local m, logical col = local n>>2,
      // physical col = logical ^ (m & 15). 2-way max.
      int mloc = ms*16 + lo16;
      Wb[mloc*16 + ((wave*4 + quad) ^ (mloc & 15))] = w ^ 0x80808080u;
    }
    __syncthreads();
    {
      // pack & store: wave = m16-chunk, lane = n within tile
      int mrow = wave*16;
      u32 ww[16];
      #pragma unroll
      for (int j = 0; j < 16; ++j)
        ww[j] = Wb[(mrow + j)*16 + (((u32)(lane >> 2)) ^ (u32)j)];
      uint4 o;
      {
        u32 p01 = __builtin_amdgcn_perm(ww[1],  ww[0],  sel1);
        u32 p23 = __builtin_amdgcn_perm(ww[3],  ww[2],  sel1);
        o.x = __builtin_amdgcn_perm(p23, p01, 0x05040100u);
        u32 p45 = __builtin_amdgcn_perm(ww[5],  ww[4],  sel1);
        u32 p67 = __builtin_amdgcn_perm(ww[7],  ww[6],  sel1);
        o.y = __builtin_amdgcn_perm(p67, p45, 0x05040100u);
        u32 p89 = __builtin_amdgcn_perm(ww[9],  ww[8],  sel1);
        u32 pab = __builtin_amdgcn_perm(ww[11], ww[10], sel1);
        o.z = __builtin_amdgcn_perm(pab, p89, 0x05040100u);
        u32 pcd = __builtin_amdgcn_perm(ww[13], ww[12], sel1);
        u32 pef = __builtin_amdgcn_perm(ww[15], ww[14], sel1);
        o.w = __builtin_amdgcn_perm(pef, pcd, 0x05040100u);
      }
      size_t mch = (size_t)(mc*32 + mt*4 + wave);
      *(uint4*)(aqB + (size_t)b*Nn*Nn + (mch*Nn + nt*64 + lane)*16) = o;
    }
  }
}

// ------------- PV GEMM (i8), lean: direct blocked aq loads, dbuf staging -------------
__global__ __launch_bounds__(256) void k_pv(const u8* __restrict__ v8, const u8* __restrict__ aqB,
                                            const int* __restrict__ vsum,
                                            const float* __restrict__ pdv, const float* __restrict__ pdw,
                                            const float* __restrict__ pzw,
                                            u16* __restrict__ h2hi, u16* __restrict__ h2lo){
  int nt = blockIdx.x, ct = blockIdx.y, b = blockIdx.z;  // tile: 64 c x 64 n
  __shared__ u8 Vt[2][64*64];
  __shared__ u8 At[2][256*16];
  int t = threadIdx.x, lane = t & 63, wave = t >> 6;
  int lo16 = lane & 15, quad = lane >> 4;

  i32x4 zi = {0,0,0,0};
  i32x4 acc[4] = {zi,zi,zi,zi};

  int vc = t >> 2, vch = t & 3;
  const u8* vrow = v8 + ((size_t)(b*Cc + ct*64 + vc))*Nn + vch*16;
  const u8* abase = aqB + (size_t)b*Nn*Nn + ((size_t)nt*64 + lane)*16;
  int vofs = (vc*64 + ((vch ^ ((vc >> 1) & 3)) << 4));
  int aofs = (wave*64 + lane)*16;

  uint4 vreg = *(const uint4*)(vrow);
  uint4 areg = *(const uint4*)(abase + (size_t)wave*Nn*16);

  for (int mt = 0; mt < 64; ++mt){
    int buf = mt & 1;
    *(uint4*)(Vt[buf] + vofs) = vreg;
    *(uint4*)(At[buf] + aofs) = areg;
    __syncthreads();
    if (mt < 63){
      vreg = *(const uint4*)(vrow + (mt+1)*64);
      areg = *(const uint4*)(abase + (size_t)((mt+1)*4 + wave)*Nn*16);
    }
    int cr = wave*16 + lo16;
    i32x4 af = *(const i32x4*)(Vt[buf] + cr*64 + ((quad ^ ((cr >> 1) & 3)) << 4));
    #pragma unroll
    for (int ns = 0; ns < 4; ++ns){
      i32x4 bf_ = *(const i32x4*)(At[buf] + (quad*64 + ns*16 + lo16)*16);
      acc[ns] = MFMA_I8(af, bf_, acc[ns]);
    }
  }
  float s = pdv[0] * pdw[0];
  float corr = s * (128.0f - pzw[0]);
  int c0 = ct*64 + wave*16 + quad*4;
  float cv[4];
  #pragma unroll
  for (int r = 0; r < 4; ++r) cv[r] = corr * (float)vsum[b*Cc + c0 + r];
  #pragma unroll
  for (int ns = 0; ns < 4; ++ns){
    int n = nt*64 + ns*16 + lo16;
    U64c Uh, Ul;
    #pragma unroll
    for (int r = 0; r < 4; ++r){
      float val = s*(float)acc[ns][r] + cv[r];
      u16 h = f2bf(val);
      Uh.u[r] = h; Ul.u[r] = f2bf(val - bf2f(h));
    }
    *(uint2*)(h2hi + ((size_t)b*Nn + n)*Cc + c0) = Uh.v;
    *(uint2*)(h2lo + ((size_t)b*Nn + n)*Cc + c0) = Ul.v;
  }
}

extern "C" void kernel_launch(void* const* d_in, const int* in_sizes, int n_in,
                              void* d_out, int out_size, void* d_ws, size_t ws_size,
                              hipStream_t stream){
  (void)in_sizes; (void)n_in; (void)out_size; (void)ws_size;
  const float* x   = (const float*)d_in[0];
  const float* gsc = (const float*)d_in[1];
  const float* gbi = (const float*)d_in[2];
  const float* wq  = (const float*)d_in[3];
  const float* bq  = (const float*)d_in[4];
  const float* wk  = (const float*)d_in[5];
  const float* bk  = (const float*)d_in[6];
  const float* wv  = (const float*)d_in[7];
  const float* bv  = (const float*)d_in[8];
  const float* wp  = (const float*)d_in[9];
  const float* bp  = (const float*)d_in[10];
  const float* dq  = (const float*)d_in[11];
  const float* zq  = (const float*)d_in[12];
  const float* dk  = (const float*)d_in[13];
  const float* zk  = (const float*)d_in[14];
  const float* dv  = (const float*)d_in[15];
  const float* zv  = (const float*)d_in[16];
  const float* dw  = (const float*)d_in[17];
  const float* zw  = (const float*)d_in[18];
  float* out = (float*)d_out;

  const size_t SZT = (size_t)Bb*Nn*Cc;
  u16* hT_hi = (u16*)d_ws;
  u16* hT_lo = hT_hi + SZT;
  u16* h2hi  = hT_lo + SZT;
  u16* h2lo  = h2hi + SZT;
  u8*  qT8   = (u8*)(h2lo + SZT);
  u8*  kT8   = qT8 + SZT;
  u8*  v8    = kT8 + SZT;
  u8*  aqB   = v8 + SZT;
  float* mu  = (float*)(aqB + (size_t)Bb*Nn*Nn);
  float* rs  = mu + 128;
  u32*  stat = (u32*)(rs + 128);
  int*  vsum = (int*)(stat + 8);
  float* Lp  = (float*)(vsum + Bb*Cc);
  float* invL= Lp + (size_t)Bb*8*Nn;

  k_gn_stats<<<dim3(Bb*NGRP), 256, 0, stream>>>(x, mu, rs);
  k_gn_apply<<<dim3(Nn/64, Cc/64, Bb), 256, 0, stream>>>(x, gsc, gbi, mu, rs, hT_hi, hT_lo);

  k_convqkv<<<dim3(Nn/64, 4, Bb), 256, 0, stream>>>(wq, wk, wv, hT_hi, hT_lo,
                                                    bq, bk, bv, dq, zq, dk, zk, dv, zv,
                                                    qT8, kT8, v8);

  hipMemsetAsync(stat, 0, 8*sizeof(u32), stream);
  k_norms<<<dim3(128), 256, 0, stream>>>(qT8, kT8, stat);
  k_vsum<<<dim3(Bb*Cc), 256, 0, stream>>>(v8, vsum);
  k_sumexp<<<dim3(Nn/64, 8, Bb), 256, 0, stream>>>(qT8, kT8, stat, dq, dk, Lp);
  k_redl<<<dim3(Bb*Nn/256), 256, 0, stream>>>(Lp, invL);
  k_quant<<<dim3(Nn/64, 8, Bb), 256, 0, stream>>>(qT8, kT8, stat, dq, dk, dw, zw, invL, aqB);

  k_pv<<<dim3(Nn/64, 4, Bb), 256, 0, stream>>>(v8, aqB, vsum, dv, dw, zw, h2hi, h2lo);

  k_conv<<<dim3(Nn/64, 4, Bb), 256, 0, stream>>>(wp, h2hi, h2lo, bp, x, out);
}

// Round 7
// 293.232 us; speedup vs baseline: 2.4305x; 1.0213x over previous
//
#include <hip/hip_runtime.h>

// QuantAttnBlock on gfx950, round 7: k_quant VALU diet (exponent-folded scale,
// cvt_pk_u8, inlined L reduction), pre-split bf16 weights, h2 single-bf16,
// merged norms/vsum. Structure otherwise identical to round 6.

#define Bb 4
#define Cc 256
#define Nn 4096
#define NGRP 32
#define LOG2E 1.4426950408889634f

typedef unsigned short u16;
typedef unsigned int   u32;
typedef unsigned char  u8;
typedef __attribute__((ext_vector_type(8))) short bf16x8;
typedef __attribute__((ext_vector_type(4))) float f32x4;
typedef __attribute__((ext_vector_type(4))) int   i32x4;

#define MFMA16(a,b,c)    __builtin_amdgcn_mfma_f32_16x16x32_bf16((a),(b),(c),0,0,0)
#define MFMA_I8(a,b,c)   __builtin_amdgcn_mfma_i32_16x16x64_i8((a),(b),(c),0,0,0)

static __device__ __forceinline__ u16 f2bf(float x){
  u32 u = __float_as_uint(x);
  u += 0x7fffu + ((u >> 16) & 1u);
  return (u16)(u >> 16);
}
static __device__ __forceinline__ float bf2f(u16 h){ return __uint_as_float(((u32)h) << 16); }

union U64c { u16 u[4]; uint2 v; };

// ---------------- GroupNorm stats ----------------
__global__ __launch_bounds__(256) void k_gn_stats(const float* __restrict__ x,
                                                  float* __restrict__ mu, float* __restrict__ rs){
  int bg = blockIdx.x;
  const float4* p = (const float4*)(x + (size_t)bg * (8 * Nn));
  float s = 0.f, q = 0.f;
  for (int i = threadIdx.x; i < 8*Nn/4; i += 256){
    float4 v = p[i];
    s += v.x + v.y + v.z + v.w;
    q += v.x*v.x + v.y*v.y + v.z*v.z + v.w*v.w;
  }
  __shared__ float rsum[256], rsq[256];
  rsum[threadIdx.x] = s; rsq[threadIdx.x] = q;
  __syncthreads();
  for (int off = 128; off > 0; off >>= 1){
    if (threadIdx.x < off){ rsum[threadIdx.x] += rsum[threadIdx.x+off]; rsq[threadIdx.x] += rsq[threadIdx.x+off]; }
    __syncthreads();
  }
  if (threadIdx.x == 0){
    const float inv = 1.0f / (8*Nn);
    float m = rsum[0]*inv;
    float var = rsq[0]*inv - m*m;
    mu[bg] = m; rs[bg] = rsqrtf(var + 1e-6f);
  }
}

// ------------- weight split: 4 matrices f32 -> hi/lo bf16 -------------
__global__ __launch_bounds__(256) void k_wsplit(const float* __restrict__ wq, const float* __restrict__ wk,
                                                const float* __restrict__ wv, const float* __restrict__ wp,
                                                u16* __restrict__ WH, u16* __restrict__ WL){
  int gid = blockIdx.x*256 + threadIdx.x;      // 0 .. 4*65536
  int mat = gid >> 16, idx = gid & 65535;
  const float* src = (mat == 0) ? wq : (mat == 1) ? wk : (mat == 2) ? wv : wp;
  float w = src[idx];
  u16 h = f2bf(w);
  WH[gid] = h;
  WL[gid] = f2bf(w - bf2f(h));
}

// ------------- GroupNorm apply + transpose -> hT hi/lo [b][n][c] -------------
__global__ __launch_bounds__(256) void k_gn_apply(const float* __restrict__ x,
                                                  const float* __restrict__ gsc, const float* __restrict__ gbi,
                                                  const float* __restrict__ mu, const float* __restrict__ rs,
                                                  u16* __restrict__ hhi, u16* __restrict__ hlo){
  int nt = blockIdx.x, ct = blockIdx.y, b = blockIdx.z;
  int n0 = nt*64, c0 = ct*64;
  __shared__ float yt[64*65];
  __shared__ float sa[64], sb[64];
  int t = threadIdx.x;
  if (t < 64){
    int c = c0 + t;
    int bg = b*NGRP + (c >> 3);
    float a = rs[bg] * gsc[c];
    sa[t] = a;
    sb[t] = gbi[c] - mu[bg]*a;
  }
  __syncthreads();
  #pragma unroll
  for (int j = 0; j < 4; ++j){
    int id = t + j*256;
    int r = id >> 4, cq = id & 15;
    float4 v = *(const float4*)(x + ((size_t)b*Cc + c0 + r)*Nn + n0 + cq*4);
    float a = sa[r], bb = sb[r];
    yt[r*65 + cq*4 + 0] = v.x*a + bb;
    yt[r*65 + cq*4 + 1] = v.y*a + bb;
    yt[r*65 + cq*4 + 2] = v.z*a + bb;
    yt[r*65 + cq*4 + 3] = v.w*a + bb;
  }
  __syncthreads();
  int nl = t >> 2, cg = (t & 3) * 16;
  size_t base = ((size_t)b*Nn + n0 + nl)*Cc + c0 + cg;
  #pragma unroll
  for (int half = 0; half < 2; ++half){
    union { u16 u[8]; uint4 v; } Ph, Pl;
    #pragma unroll
    for (int u = 0; u < 8; ++u){
      float y = yt[(cg + half*8 + u)*65 + nl];
      u16 h = f2bf(y);
      Ph.u[u] = h; Pl.u[u] = f2bf(y - bf2f(h));
    }
    *(uint4*)(hhi + base + half*8) = Ph.v;
    *(uint4*)(hlo + base + half*8) = Pl.v;
  }
}

// ------------- Fused QKV conv GEMM (bf16 hi/lo, ~fp32 accurate) -------------
__global__ __launch_bounds__(256) void k_convqkv(const u16* __restrict__ WH, const u16* __restrict__ WL,
                                                 const u16* __restrict__ Hhi, const u16* __restrict__ Hlo,
                                                 const float* __restrict__ bq, const float* __restrict__ bk,
                                                 const float* __restrict__ bv,
                                                 const float* __restrict__ dq, const float* __restrict__ zq,
                                                 const float* __restrict__ dk, const float* __restrict__ zk,
                                                 const float* __restrict__ dv, const float* __restrict__ zv,
                                                 u8* __restrict__ qT8, u8* __restrict__ kT8,
                                                 u8* __restrict__ v8){
  int nt = blockIdx.x, ot = blockIdx.y, b = blockIdx.z;
  __shared__ u16 Lh[64*256], Ll[64*256];
  int t = threadIdx.x, lane = t & 63, wave = t >> 6;
  int lo16 = lane & 15, quad = lane >> 4;
  int o0 = ot*64 + wave*16;

  {
    const u16* hb = Hhi + ((size_t)b*Nn + nt*64) * 256;
    const u16* lb = Hlo + ((size_t)b*Nn + nt*64) * 256;
    #pragma unroll
    for (int j = 0; j < 8; ++j){
      int id = t + j*256;
      int r = id >> 5, ch = id & 31;
      int sw = (ch ^ (r & 15)) * 8;
      *(uint4*)(Lh + r*256 + sw) = *(const uint4*)(hb + (size_t)r*256 + ch*8);
      *(uint4*)(Ll + r*256 + sw) = *(const uint4*)(lb + (size_t)r*256 + ch*8);
    }
  }
  __syncthreads();

  const float* Bs[3] = {bq, bk, bv};
  const float* Dsr[3] = {dq, dk, dv};
  const float* Zs[3] = {zq, zk, zv};

  #pragma unroll
  for (int ws = 0; ws < 3; ++ws){
    bf16x8 awh[8], awl[8];
    {
      const u16* wbh = WH + (size_t)ws*65536 + (size_t)(o0 + lo16) * 256 + quad*8;
      const u16* wbl = WL + (size_t)ws*65536 + (size_t)(o0 + lo16) * 256 + quad*8;
      #pragma unroll
      for (int k = 0; k < 8; ++k){
        awh[k] = *(const bf16x8*)(wbh + k*32);
        awl[k] = *(const bf16x8*)(wbl + k*32);
      }
    }
    f32x4 zf = {0.f,0.f,0.f,0.f};
    f32x4 acc[4] = {zf, zf, zf, zf};
    #pragma unroll
    for (int k = 0; k < 8; ++k){
      #pragma unroll
      for (int ns = 0; ns < 4; ++ns){
        int r = ns*16 + lo16;
        int ph = ((k*4 + quad) ^ (r & 15)) * 8;
        bf16x8 bh = *(const bf16x8*)(Lh + r*256 + ph);
        bf16x8 bl = *(const bf16x8*)(Ll + r*256 + ph);
        acc[ns] = MFMA16(awh[k], bh, acc[ns]);
        acc[ns] = MFMA16(awl[k], bh, acc[ns]);
        acc[ns] = MFMA16(awh[k], bl, acc[ns]);
      }
    }
    float bia[4];
    #pragma unroll
    for (int r = 0; r < 4; ++r) bia[r] = Bs[ws][o0 + quad*4 + r];
    float z = Zs[ws][0]; float invd = 1.0f / Dsr[ws][0];

    if (ws < 2){
      u8* outT = (ws == 0) ? qT8 : kT8;
      #pragma unroll
      for (int ns = 0; ns < 4; ++ns){
        int n = nt*64 + ns*16 + lo16;
        u32 w = 0;
        #pragma unroll
        for (int r = 0; r < 4; ++r){
          float v = acc[ns][r] + bia[r];
          float xq = fminf(fmaxf(rintf(v*invd) + z, 0.f), 255.f);
          int qi = (int)rintf(xq - z);
          w |= ((u32)(qi & 255)) << (8*r);
        }
        *(u32*)(outT + ((size_t)b*Nn + n)*Cc + o0 + quad*4) = w;
      }
    } else {
      #pragma unroll
      for (int ns = 0; ns < 4; ++ns){
        int n = nt*64 + ns*16 + lo16;
        #pragma unroll
        for (int r = 0; r < 4; ++r){
          float v = acc[ns][r] + bia[r];
          float xq = fminf(fmaxf(rintf(v*invd) + z, 0.f), 255.f);
          int qi = (int)rintf(xq - z);
          v8[((size_t)b*Cc + o0 + quad*4 + r)*Nn + n] = (u8)(qi & 255);
        }
      }
    }
  }
}

// ------------- proj conv (pre-split W hi/lo, single-bf16 H) + residual -> f32 out -------------
__global__ __launch_bounds__(256) void k_conv(const u16* __restrict__ WH, const u16* __restrict__ WL,
                                              const u16* __restrict__ Hh,
                                              const float* __restrict__ bias,
                                              const float* __restrict__ xres, float* __restrict__ outF){
  int nt = blockIdx.x, ot = blockIdx.y, b = blockIdx.z;
  __shared__ u16 Lh[64*128];
  int t = threadIdx.x, lane = t & 63, wave = t >> 6;
  int lo16 = lane & 15, quad = lane >> 4;
  int o0 = ot*64 + wave*16;

  bf16x8 awh[8], awl[8];
  {
    const u16* wbh = WH + (size_t)3*65536 + (size_t)(o0 + lo16) * 256 + quad*8;
    const u16* wbl = WL + (size_t)3*65536 + (size_t)(o0 + lo16) * 256 + quad*8;
    #pragma unroll
    for (int k = 0; k < 8; ++k){
      awh[k] = *(const bf16x8*)(wbh + k*32);
      awl[k] = *(const bf16x8*)(wbl + k*32);
    }
  }
  f32x4 zf = {0.f,0.f,0.f,0.f};
  f32x4 acc[4] = {zf, zf, zf, zf};

  const u16* hb = Hh + ((size_t)b*Nn + nt*64) * 256;
  for (int kc = 0; kc < 2; ++kc){
    __syncthreads();
    for (int id = t; id < 64*16; id += 256){
      int r = id >> 4, ch = id & 15;
      int sw = (ch ^ (r & 7)) * 8;
      *(uint4*)(Lh + r*128 + sw) = *(const uint4*)(hb + (size_t)r*256 + kc*128 + ch*8);
    }
    __syncthreads();
    #pragma unroll
    for (int k4 = 0; k4 < 4; ++k4){
      int k = kc*4 + k4;
      #pragma unroll
      for (int ns = 0; ns < 4; ++ns){
        int r = ns*16 + lo16;
        int ch = ((k4*4 + quad) ^ (r & 7)) * 8;
        bf16x8 bh = *(const bf16x8*)(Lh + r*128 + ch);
        acc[ns] = MFMA16(awh[k], bh, acc[ns]);
        acc[ns] = MFMA16(awl[k], bh, acc[ns]);
      }
    }
  }

  float bia[4];
  #pragma unroll
  for (int r = 0; r < 4; ++r) bia[r] = bias[o0 + quad*4 + r];
  #pragma unroll
  for (int ns = 0; ns < 4; ++ns){
    int n = nt*64 + ns*16 + lo16;
    #pragma unroll
    for (int r = 0; r < 4; ++r){
      size_t a = ((size_t)b*Cc + o0 + quad*4 + r)*Nn + n;
      outF[a] = xres[a] + acc[ns][r] + bia[r];
    }
  }
}

static __device__ __forceinline__ void stage64x256(u8* dst, const u8* __restrict__ src, int t){
  #pragma unroll
  for (int j = 0; j < 4; ++j){
    int id = t + j*256; int r = id >> 4, ch = id & 15;
    *(uint4*)(dst + r*256 + ((ch ^ (r & 15)) << 4)) = *(const uint4*)(src + r*256 + ch*16);
  }
}

// ------------- merged: row norm^2 max (blocks 0..127) + vsum (blocks 128..1151) -------------
static __device__ __forceinline__ int sq4(u32 w){
  int s = 0;
  #pragma unroll
  for (int j = 0; j < 4; ++j){ int v = (int)((signed char)((w >> (8*j)) & 0xffu)); s += v*v; }
  return s;
}
static __device__ __forceinline__ int ssum4(u32 w){
  return ((int)(w << 24) >> 24) + ((int)(w << 16) >> 24) + ((int)(w << 8) >> 24) + ((int)w >> 24);
}
__global__ __launch_bounds__(256) void k_normvs(const u8* __restrict__ qT8, const u8* __restrict__ kT8,
                                                const u8* __restrict__ v8,
                                                u32* __restrict__ stat, int* __restrict__ vsum){
  if (blockIdx.x < 128){
    int gid = blockIdx.x*256 + threadIdx.x;
    int which = gid >> 14;
    int rid = gid & 16383;
    const u8* row = (which ? kT8 : qT8) + (size_t)rid * 256;
    u32 acc = 0;
    const uint4* p = (const uint4*)row;
    #pragma unroll
    for (int i = 0; i < 16; ++i){
      uint4 w = p[i];
      acc += (u32)(sq4(w.x) + sq4(w.y) + sq4(w.z) + sq4(w.w));
    }
    #pragma unroll
    for (int msk = 32; msk > 0; msk >>= 1){
      u32 o = (u32)__shfl_xor((int)acc, msk, 64);
      acc = acc > o ? acc : o;
    }
    if ((threadIdx.x & 63) == 0)
      atomicMax(&stat[which*4 + (rid >> 12)], acc);
  } else {
    int row = blockIdx.x - 128;                // b*Cc + c
    uint4 w = *(const uint4*)(v8 + (size_t)row*Nn + threadIdx.x*16);
    int s = ssum4(w.x) + ssum4(w.y) + ssum4(w.z) + ssum4(w.w);
    #pragma unroll
    for (int msk = 1; msk < 64; msk <<= 1) s += __shfl_xor(s, msk, 64);
    __shared__ int r4[4];
    if ((threadIdx.x & 63) == 0) r4[threadIdx.x >> 6] = s;
    __syncthreads();
    if (threadIdx.x == 0) vsum[row] = r4[0] + r4[1] + r4[2] + r4[3];
  }
}

// ------------- sum-exp pass -------------
__global__ __launch_bounds__(256) void k_sumexp(const u8* __restrict__ qT8, const u8* __restrict__ kT8,
                                                const u32* __restrict__ stat,
                                                const float* __restrict__ pdq, const float* __restrict__ pdk,
                                                float* __restrict__ Lp){
  int nt = blockIdx.x, mc = blockIdx.y, b = blockIdx.z;
  __shared__ u8 Kt[64*256];
  int t = threadIdx.x, lane = t & 63, wave = t >> 6;
  int lo16 = lane & 15, quad = lane >> 4;

  i32x4 a[4];
  {
    const u8* qb = qT8 + ((size_t)b*Nn + nt*64)*256;
    int ar = wave*16 + lo16;
    #pragma unroll
    for (int k = 0; k < 4; ++k)
      a[k] = *(const i32x4*)(qb + ar*256 + (k*4 + quad)*16);
  }
  float sc2 = pdq[0]*pdk[0]*0.0625f*LOG2E;
  float M2 = sc2 * sqrtf((float)stat[b] * (float)stat[4+b]);
  float lr[4] = {0.f,0.f,0.f,0.f};

  const u8* kbase = kT8 + ((size_t)b*Nn + mc*512)*256;
  for (int mt = 0; mt < 8; ++mt){
    __syncthreads();
    stage64x256(Kt, kbase + (size_t)mt*64*256, t);
    __syncthreads();
    #pragma unroll
    for (int ms = 0; ms < 4; ++ms){
      i32x4 acc = {0,0,0,0};
      int br = ms*16 + lo16;
      #pragma unroll
      for (int k = 0; k < 4; ++k){
        i32x4 bk_ = *(const i32x4*)(Kt + br*256 + (((k*4 + quad) ^ (br & 15)) << 4));
        acc = MFMA_I8(a[k], bk_, acc);
      }
      #pragma unroll
      for (int r = 0; r < 4; ++r)
        lr[r] += exp2f(fmaf((float)acc[r], sc2, -M2));
    }
  }
  #pragma unroll
  for (int msk = 1; msk < 16; msk <<= 1){
    #pragma unroll
    for (int r = 0; r < 4; ++r) lr[r] += __shfl_xor(lr[r], msk, 64);
  }
  if (lo16 == 0){
    #pragma unroll
    for (int r = 0; r < 4; ++r)
      Lp[((size_t)(b*8 + mc))*Nn + nt*64 + wave*16 + quad*4 + r] = lr[r];
  }
}

// ------------- quant pass: attn^T quantize (sr folded into exponent,
// cvt_pk_u8 pack, L reduced inline), LDS transpose, blocked store -------------
__global__ __launch_bounds__(256) void k_quant(const u8* __restrict__ qT8, const u8* __restrict__ kT8,
                                               const u32* __restrict__ stat,
                                               const float* __restrict__ pdq, const float* __restrict__ pdk,
                                               const float* __restrict__ pdw, const float* __restrict__ pzw,
                                               const float* __restrict__ Lp,
                                               u8* __restrict__ aqB){
  int nt = blockIdx.x, mc = blockIdx.y, b = blockIdx.z;
  __shared__ u8 Kt[64*256];
  __shared__ u32 Wb[64*16];
  int t = threadIdx.x, lane = t & 63, wave = t >> 6;
  int lo16 = lane & 15, quad = lane >> 4;

  i32x4 a[4];
  {
    const u8* qb = qT8 + ((size_t)b*Nn + nt*64)*256;
    int ar = wave*16 + lo16;
    #pragma unroll
    for (int k = 0; k < 4; ++k)
      a[k] = *(const i32x4*)(qb + ar*256 + (k*4 + quad)*16);
  }
  float sc2 = pdq[0]*pdk[0]*0.0625f*LOG2E;
  float M2 = sc2 * sqrtf((float)stat[b] * (float)stat[4+b]);
  float invdw = 1.0f / pdw[0];
  float zw = pzw[0];
  int n0 = nt*64 + wave*16 + quad*4;
  // reduce Lp inline (was k_redl)
  float4 Ls = {0.f,0.f,0.f,0.f};
  #pragma unroll
  for (int mcc = 0; mcc < 8; ++mcc){
    float4 v = *(const float4*)(Lp + ((size_t)(b*8 + mcc))*Nn + n0);
    Ls.x += v.x; Ls.y += v.y; Ls.z += v.z; Ls.w += v.w;
  }
  // cr[r] = log2(invdw / L[r]) - M2 ; at = exp2(acc*sc2 + cr)
  float cr[4] = { __log2f(invdw/Ls.x) - M2, __log2f(invdw/Ls.y) - M2,
                  __log2f(invdw/Ls.z) - M2, __log2f(invdw/Ls.w) - M2 };
  u32 bsel = (u32)(lane & 3);
  u32 sel1 = 0x0C0C0000u | ((4u + bsel) << 8) | bsel;

  const u8* kbase = kT8 + ((size_t)b*Nn + mc*512)*256;
  for (int mt = 0; mt < 8; ++mt){
    __syncthreads();
    stage64x256(Kt, kbase + (size_t)mt*64*256, t);
    __syncthreads();
    #pragma unroll
    for (int ms = 0; ms < 4; ++ms){
      i32x4 acc = {0,0,0,0};
      int br = ms*16 + lo16;
      #pragma unroll
      for (int k = 0; k < 4; ++k){
        i32x4 bk_ = *(const i32x4*)(Kt + br*256 + (((k*4 + quad) ^ (br & 15)) << 4));
        acc = MFMA_I8(a[k], bk_, acc);
      }
      u32 w = 0;
      #pragma unroll
      for (int r = 0; r < 4; ++r){
        float at = exp2f(fmaf((float)acc[r], sc2, cr[r]));
        float y = fminf(fmaxf(rintf(at) + zw, 0.f), 255.f);
        w = __builtin_amdgcn_cvt_pk_u8_f32(y, (u32)r, w);
      }
      int mloc = ms*16 + lo16;
      Wb[mloc*16 + ((wave*4 + quad) ^ (mloc & 15))] = w ^ 0x80808080u;
    }
    __syncthreads();
    {
      int mrow = wave*16;
      u32 ww[16];
      #pragma unroll
      for (int j = 0; j < 16; ++j)
        ww[j] = Wb[(mrow + j)*16 + (((u32)(lane >> 2)) ^ (u32)j)];
      uint4 o;
      {
        u32 p01 = __builtin_amdgcn_perm(ww[1],  ww[0],  sel1);
        u32 p23 = __builtin_amdgcn_perm(ww[3],  ww[2],  sel1);
        o.x = __builtin_amdgcn_perm(p23, p01, 0x05040100u);
        u32 p45 = __builtin_amdgcn_perm(ww[5],  ww[4],  sel1);
        u32 p67 = __builtin_amdgcn_perm(ww[7],  ww[6],  sel1);
        o.y = __builtin_amdgcn_perm(p67, p45, 0x05040100u);
        u32 p89 = __builtin_amdgcn_perm(ww[9],  ww[8],  sel1);
        u32 pab = __builtin_amdgcn_perm(ww[11], ww[10], sel1);
        o.z = __builtin_amdgcn_perm(pab, p89, 0x05040100u);
        u32 pcd = __builtin_amdgcn_perm(ww[13], ww[12], sel1);
        u32 pef = __builtin_amdgcn_perm(ww[15], ww[14], sel1);
        o.w = __builtin_amdgcn_perm(pef, pcd, 0x05040100u);
      }
      size_t mch = (size_t)(mc*32 + mt*4 + wave);
      *(uint4*)(aqB + (size_t)b*Nn*Nn + (mch*Nn + nt*64 + lane)*16) = o;
    }
  }
}

// ------------- PV GEMM (i8), lean, single-bf16 output -------------
__global__ __launch_bounds__(256) void k_pv(const u8* __restrict__ v8, const u8* __restrict__ aqB,
                                            const int* __restrict__ vsum,
                                            const float* __restrict__ pdv, const float* __restrict__ pdw,
                                            const float* __restrict__ pzw,
                                            u16* __restrict__ h2){
  int nt = blockIdx.x, ct = blockIdx.y, b = blockIdx.z;  // tile: 64 c x 64 n
  __shared__ u8 Vt[2][64*64];
  __shared__ u8 At[2][256*16];
  int t = threadIdx.x, lane = t & 63, wave = t >> 6;
  int lo16 = lane & 15, quad = lane >> 4;

  i32x4 zi = {0,0,0,0};
  i32x4 acc[4] = {zi,zi,zi,zi};

  int vc = t >> 2, vch = t & 3;
  const u8* vrow = v8 + ((size_t)(b*Cc + ct*64 + vc))*Nn + vch*16;
  const u8* abase = aqB + (size_t)b*Nn*Nn + ((size_t)nt*64 + lane)*16;
  int vofs = (vc*64 + ((vch ^ ((vc >> 1) & 3)) << 4));
  int aofs = (wave*64 + lane)*16;

  uint4 vreg = *(const uint4*)(vrow);
  uint4 areg = *(const uint4*)(abase + (size_t)wave*Nn*16);

  for (int mt = 0; mt < 64; ++mt){
    int buf = mt & 1;
    *(uint4*)(Vt[buf] + vofs) = vreg;
    *(uint4*)(At[buf] + aofs) = areg;
    __syncthreads();
    if (mt < 63){
      vreg = *(const uint4*)(vrow + (mt+1)*64);
      areg = *(const uint4*)(abase + (size_t)((mt+1)*4 + wave)*Nn*16);
    }
    int cr = wave*16 + lo16;
    i32x4 af = *(const i32x4*)(Vt[buf] + cr*64 + ((quad ^ ((cr >> 1) & 3)) << 4));
    #pragma unroll
    for (int ns = 0; ns < 4; ++ns){
      i32x4 bf_ = *(const i32x4*)(At[buf] + (quad*64 + ns*16 + lo16)*16);
      acc[ns] = MFMA_I8(af, bf_, acc[ns]);
    }
  }
  float s = pdv[0] * pdw[0];
  float corr = s * (128.0f - pzw[0]);
  int c0 = ct*64 + wave*16 + quad*4;
  float cv[4];
  #pragma unroll
  for (int r = 0; r < 4; ++r) cv[r] = corr * (float)vsum[b*Cc + c0 + r];
  #pragma unroll
  for (int ns = 0; ns < 4; ++ns){
    int n = nt*64 + ns*16 + lo16;
    U64c Uh;
    #pragma unroll
    for (int r = 0; r < 4; ++r)
      Uh.u[r] = f2bf(s*(float)acc[ns][r] + cv[r]);
    *(uint2*)(h2 + ((size_t)b*Nn + n)*Cc + c0) = Uh.v;
  }
}

extern "C" void kernel_launch(void* const* d_in, const int* in_sizes, int n_in,
                              void* d_out, int out_size, void* d_ws, size_t ws_size,
                              hipStream_t stream){
  (void)in_sizes; (void)n_in; (void)out_size; (void)ws_size;
  const float* x   = (const float*)d_in[0];
  const float* gsc = (const float*)d_in[1];
  const float* gbi = (const float*)d_in[2];
  const float* wq  = (const float*)d_in[3];
  const float* bq  = (const float*)d_in[4];
  const float* wk  = (const float*)d_in[5];
  const float* bk  = (const float*)d_in[6];
  const float* wv  = (const float*)d_in[7];
  const float* bv  = (const float*)d_in[8];
  const float* wp  = (const float*)d_in[9];
  const float* bp  = (const float*)d_in[10];
  const float* dq  = (const float*)d_in[11];
  const float* zq  = (const float*)d_in[12];
  const float* dk  = (const float*)d_in[13];
  const float* zk  = (const float*)d_in[14];
  const float* dv  = (const float*)d_in[15];
  const float* zv  = (const float*)d_in[16];
  const float* dw  = (const float*)d_in[17];
  const float* zw  = (const float*)d_in[18];
  float* out = (float*)d_out;

  const size_t SZT = (size_t)Bb*Nn*Cc;
  u16* hT_hi = (u16*)d_ws;
  u16* hT_lo = hT_hi + SZT;
  u16* h2    = hT_lo + SZT;
  u8*  qT8   = (u8*)(h2 + SZT);
  u8*  kT8   = qT8 + SZT;
  u8*  v8    = kT8 + SZT;
  u8*  aqB   = v8 + SZT;
  u16* WH    = (u16*)(aqB + (size_t)Bb*Nn*Nn);
  u16* WL    = WH + 4*65536;
  float* mu  = (float*)(WL + 4*65536);
  float* rs  = mu + 128;
  u32*  stat = (u32*)(rs + 128);
  int*  vsum = (int*)(stat + 8);
  float* Lp  = (float*)(vsum + Bb*Cc);

  k_gn_stats<<<dim3(Bb*NGRP), 256, 0, stream>>>(x, mu, rs);
  k_wsplit<<<dim3(1024), 256, 0, stream>>>(wq, wk, wv, wp, WH, WL);
  k_gn_apply<<<dim3(Nn/64, Cc/64, Bb), 256, 0, stream>>>(x, gsc, gbi, mu, rs, hT_hi, hT_lo);

  k_convqkv<<<dim3(Nn/64, 4, Bb), 256, 0, stream>>>(WH, WL, hT_hi, hT_lo,
                                                    bq, bk, bv, dq, zq, dk, zk, dv, zv,
                                                    qT8, kT8, v8);

  hipMemsetAsync(stat, 0, 8*sizeof(u32), stream);
  k_normvs<<<dim3(128 + Bb*Cc), 256, 0, stream>>>(qT8, kT8, v8, stat, vsum);
  k_sumexp<<<dim3(Nn/64, 8, Bb), 256, 0, stream>>>(qT8, kT8, stat, dq, dk, Lp);
  k_quant<<<dim3(Nn/64, 8, Bb), 256, 0, stream>>>(qT8, kT8, stat, dq, dk, dw, zw, Lp, aqB);

  k_pv<<<dim3(Nn/64, 4, Bb), 256, 0, stream>>>(v8, aqB, vsum, dv, dw, zw, h2);

  k_conv<<<dim3(Nn/64, 4, Bb), 256, 0, stream>>>(WH, WL, h2, bp, x, out);
}